// Round 8
// baseline (328.622 us; speedup 1.0000x reference)
//
#include <hip/hip_runtime.h>
#include <hip/hip_bf16.h>
#include <cstddef>

typedef __attribute__((ext_vector_type(8))) short bf16x8;
typedef __attribute__((ext_vector_type(4))) float f32x4;

#define NCH_ 512
#define NRM_ 0.35355339059327373f  // 64^-0.25
#define RATIO_ 0.0625f             // 256^-0.5
#define MFMA(a,b,c) __builtin_amdgcn_mfma_f32_16x16x32_bf16((a),(b),(c),0,0,0)

__device__ __forceinline__ unsigned short f2b(float f) {
  unsigned u = __float_as_uint(f);
  u += 0x7FFFu + ((u >> 16) & 1u);
  return (unsigned short)(u >> 16);
}
__device__ __forceinline__ float b2f(unsigned short h) {
  return __uint_as_float(((unsigned)h) << 16);
}
__device__ __forceinline__ unsigned pk2f(float a, float b) {
  union { __hip_bfloat162 h; unsigned u; } cv;
  cv.h = __float22bfloat162_rn(make_float2(a, b));
  return cv.u;
}
__device__ __forceinline__ bf16x8 cvt8(float4 a, float4 b) {
  union { bf16x8 v; unsigned u[4]; } r;
  r.u[0]=pk2f(a.x,a.y); r.u[1]=pk2f(a.z,a.w);
  r.u[2]=pk2f(b.x,b.y); r.u[3]=pk2f(b.z,b.w);
  return r.v;
}
__device__ __forceinline__ float sumsq4(float4 a){ return a.x*a.x+a.y*a.y+a.z*a.z+a.w*a.w; }
__device__ __forceinline__ float4 sc4(float4 f){ return make_float4(NRM_*f.x,NRM_*f.y,NRM_*f.z,NRM_*f.w); }

// Persistent-grid barrier: single-use counter per barrier instance.
// All 512 blocks are co-resident (2/CU via __launch_bounds__(256,2), LDS 67.9KB*2 < 160KB).
__device__ __forceinline__ void gbar(unsigned* bar) {
  __syncthreads();
  if (threadIdx.x == 0) {
    __threadfence();                    // agent release: drain + L2 writeback
    atomicAdd(bar, 1u);                 // device-scope RMW
    while (__hip_atomic_load(bar, __ATOMIC_ACQUIRE, __HIP_MEMORY_SCOPE_AGENT) < NCH_)
      __builtin_amdgcn_s_sleep(8);
    __threadfence();                    // agent acquire: L2 invalidate
  }
  __syncthreads();
}

__global__ void init_kernel(unsigned* bar) {
  if (threadIdx.x < 8) bar[threadIdx.x] = 0u;
}

// One persistent block per 64-row chunk. LDS regions:
//  A_ 36,864B : proj u16[256][72] -> qS/kpS u16[64][264] -> oT f32[64][68]
//  Bf 18,432B : x f32[64][72] -> kpT u16[128][72] -> P u16[64][72]
//  C_ 11,520B : vext u16[80][72] (alive whole kernel)
//  rmS 1KB + kmS
__global__ __launch_bounds__(256, 2) void fused_kernel(
    const float* __restrict__ qg, const float* __restrict__ kg,
    const float* __restrict__ vg, const float* __restrict__ projg,
    float* __restrict__ blockmax, unsigned short* __restrict__ kvxP,
    unsigned short* __restrict__ sxP, float* __restrict__ out_g,
    unsigned* __restrict__ bar)
{
  __shared__ __align__(16) unsigned char lds[36864 + 18432 + 11520 + 1024 + 16];
  unsigned short* A_  = (unsigned short*)lds;
  float*          Bf  = (float*)(lds + 36864);
  unsigned short* Bu  = (unsigned short*)Bf;
  unsigned short* C_  = (unsigned short*)(lds + 36864 + 18432);
  float*          rmS = (float*)(lds + 36864 + 18432 + 11520);   // [4][64]
  float*          kmS = rmS + 256;

  const int t = threadIdx.x, ch = blockIdx.x;
  const int row0 = ch*64;
  const int lane=t&63, m16=lane&15, q4=lane>>4, w=t>>6;
  const int f0 = w*64, r0 = w*16;

  // ================= phase A: stage proj + k-x + vext =================
#pragma unroll
  for (int i=0;i<8;++i){ int flat=i*2048+t*8; int f=flat>>6, d2=flat&63;
    float4 p0 = *(const float4*)(projg+flat);
    float4 p1 = *(const float4*)(projg+flat+4);
    *(uint4*)&A_[f*72+d2] = make_uint4(pk2f(p0.x,p0.y),pk2f(p0.z,p0.w),
                                       pk2f(p1.x,p1.y),pk2f(p1.z,p1.w)); }
  {
    const float* xg2 = kg + (size_t)row0*64;
#pragma unroll
    for (int i=0;i<4;++i){ int flat=i*1024+t*4; int r=flat>>6, d2=flat&63;
      *(float4*)&Bf[r*72+d2] = *(const float4*)(xg2+flat); }
  }
  {
    int c = t&63, sq_ = t>>6;
#pragma unroll
    for (int i=0;i<16;++i)
      C_[c*72 + sq_*16 + i] = f2b(vg[((size_t)row0 + sq_*16 + i)*64 + c]);
    int cc = 64 + (t>>4), s4 = (t&15)*4;
    unsigned short hv = (cc==64) ? (unsigned short)0x3F80 : (unsigned short)0;
    unsigned pv = (unsigned)hv | ((unsigned)hv<<16);
    *(uint2*)&C_[cc*72 + s4] = make_uint2(pv, pv);
  }
  __syncthreads();

  // ---- k diag + frags + GEMM (acc held across grid barrier) ----
  float kdiag4[4];
  f32x4 kacc[4][4];
  {
    bf16x8 kb[4][2];
#pragma unroll
    for (int rt=0;rt<4;++rt){
      const float* xr = &Bf[(rt*16+m16)*72 + q4*8];
      float4 x0=*(const float4*)(xr), x1=*(const float4*)(xr+4);
      float4 x2=*(const float4*)(xr+32), x3=*(const float4*)(xr+36);
      float sq = sumsq4(x0)+sumsq4(x1)+sumsq4(x2)+sumsq4(x3);
      sq += __shfl_xor(sq,16); sq += __shfl_xor(sq,32);
      kdiag4[rt] = 0.0625f*sq;
      kb[rt][0]=cvt8(sc4(x0),sc4(x1)); kb[rt][1]=cvt8(sc4(x2),sc4(x3));
    }
#pragma unroll
    for (int rt=0;rt<4;++rt)
#pragma unroll
      for (int mt=0;mt<4;++mt) kacc[rt][mt] = (f32x4){0.f,0.f,0.f,0.f};
#pragma unroll
    for (int kk=0;kk<2;++kk)
#pragma unroll
      for (int mt=0;mt<4;++mt){
        bf16x8 a = *(const bf16x8*)&A_[(f0+mt*16+m16)*72 + kk*32 + q4*8];
#pragma unroll
        for (int rt=0;rt<4;++rt)
          kacc[rt][mt] = MFMA(a, kb[rt][kk], kacc[rt][mt]);
      }
  }
  __syncthreads();   // all k-x reads of Bf done

  // ---- q: stage, GEMM, rowmax, exp -> qS, A-frags to regs ----
  {
    const float* xg2 = qg + (size_t)row0*64;
#pragma unroll
    for (int i=0;i<4;++i){ int flat=i*1024+t*4; int r=flat>>6, d2=flat&63;
      *(float4*)&Bf[r*72+d2] = *(const float4*)(xg2+flat); }
  }
  __syncthreads();
  bf16x8 aq[8];
  {
    float qdiag4[4];
    f32x4 qacc[4][4];
    bf16x8 qb[4][2];
#pragma unroll
    for (int rt=0;rt<4;++rt){
      const float* xr = &Bf[(rt*16+m16)*72 + q4*8];
      float4 x0=*(const float4*)(xr), x1=*(const float4*)(xr+4);
      float4 x2=*(const float4*)(xr+32), x3=*(const float4*)(xr+36);
      float sq = sumsq4(x0)+sumsq4(x1)+sumsq4(x2)+sumsq4(x3);
      sq += __shfl_xor(sq,16); sq += __shfl_xor(sq,32);
      qdiag4[rt] = 0.0625f*sq;
      qb[rt][0]=cvt8(sc4(x0),sc4(x1)); qb[rt][1]=cvt8(sc4(x2),sc4(x3));
    }
#pragma unroll
    for (int rt=0;rt<4;++rt)
#pragma unroll
      for (int mt=0;mt<4;++mt) qacc[rt][mt] = (f32x4){0.f,0.f,0.f,0.f};
#pragma unroll
    for (int kk=0;kk<2;++kk)
#pragma unroll
      for (int mt=0;mt<4;++mt){
        bf16x8 a = *(const bf16x8*)&A_[(f0+mt*16+m16)*72 + kk*32 + q4*8];
#pragma unroll
        for (int rt=0;rt<4;++rt)
          qacc[rt][mt] = MFMA(a, qb[rt][kk], qacc[rt][mt]);
      }
    // per-row max across features (this wave's 64-feat slice, then cross-wave)
#pragma unroll
    for (int rt=0;rt<4;++rt){
      float p = qacc[rt][0][0];
#pragma unroll
      for (int mt=0;mt<4;++mt)
#pragma unroll
        for (int j=0;j<4;++j) p = fmaxf(p, qacc[rt][mt][j]);
      p = fmaxf(p, __shfl_xor(p,16)); p = fmaxf(p, __shfl_xor(p,32));
      if (q4 == 0) rmS[w*64 + rt*16+m16] = p;
    }
    __syncthreads();   // rmS ready; all proj reads of A_ done
    unsigned short* qS = A_;
#pragma unroll
    for (int rt=0;rt<4;++rt){
      int rr = rt*16+m16;
      float rm = fmaxf(fmaxf(rmS[rr],rmS[64+rr]),fmaxf(rmS[128+rr],rmS[192+rr]));
      float e = qdiag4[rt] + rm;
#pragma unroll
      for (int mt=0;mt<4;++mt){
        float v0 = RATIO_*(__expf(qacc[rt][mt][0]-e)+1e-4f);
        float v1 = RATIO_*(__expf(qacc[rt][mt][1]-e)+1e-4f);
        float v2 = RATIO_*(__expf(qacc[rt][mt][2]-e)+1e-4f);
        float v3 = RATIO_*(__expf(qacc[rt][mt][3]-e)+1e-4f);
        *(uint2*)&qS[rr*264 + f0 + mt*16 + q4*4] = make_uint2(pk2f(v0,v1), pk2f(v2,v3));
      }
    }
    __syncthreads();
#pragma unroll
    for (int kk=0;kk<8;++kk)
      aq[kk] = *(const bf16x8*)&qS[(r0+m16)*264 + kk*32 + q4*8];
  }
  // ---- k chunk max -> blockmax ----
  {
    float mx = kacc[0][0][0];
#pragma unroll
    for (int rt=0;rt<4;++rt)
#pragma unroll
      for (int mt=0;mt<4;++mt)
#pragma unroll
        for (int j=0;j<4;++j) mx = fmaxf(mx, kacc[rt][mt][j]);
#pragma unroll
    for (int off=1; off<64; off<<=1) mx = fmaxf(mx, __shfl_xor(mx, off));
    if (lane == 0) rmS[w*64] = mx;
    __syncthreads();
    if (t == 0)
      blockmax[ch] = fmaxf(fmaxf(rmS[0],rmS[64]),fmaxf(rmS[128],rmS[192]));
  }
  gbar(bar + 0);   // ============ SYNC 1 ============

  // ================= phase B: k' exp + chunk-sum GEMM =================
  if (t < 32) {
    float bm = blockmax[(ch>>5)*32 + t];
#pragma unroll
    for (int off=16; off>=1; off>>=1) bm = fmaxf(bm, __shfl_xor(bm, off));
    if (t == 0) *kmS = bm;
  }
  __syncthreads();
  const float kmx = *kmS;
  unsigned short* kpS = A_;   // qS dead (aq in regs)
  unsigned short* kpT = Bu;
  unsigned kpx[4][4][2];
#pragma unroll
  for (int rt=0;rt<4;++rt){
    float e = kdiag4[rt] + kmx;
    int rr = rt*16+m16;
#pragma unroll
    for (int mt=0;mt<4;++mt){
      float v0 = RATIO_*(__expf(kacc[rt][mt][0]-e)+1e-4f);
      float v1 = RATIO_*(__expf(kacc[rt][mt][1]-e)+1e-4f);
      float v2 = RATIO_*(__expf(kacc[rt][mt][2]-e)+1e-4f);
      float v3 = RATIO_*(__expf(kacc[rt][mt][3]-e)+1e-4f);
      kpx[rt][mt][0] = pk2f(v0,v1); kpx[rt][mt][1] = pk2f(v2,v3);
      *(uint2*)&kpS[rr*264 + f0 + mt*16 + q4*4] = make_uint2(kpx[rt][mt][0], kpx[rt][mt][1]);
    }
  }
  if ((w>>1) == 0) {   // kpT half 0 (features 0..127)
#pragma unroll
    for (int rt=0;rt<4;++rt)
#pragma unroll
      for (int mt=0;mt<4;++mt)
#pragma unroll
        for (int jp=0;jp<2;++jp){
          int frl = (w&1)*64 + mt*16 + q4*4 + jp*2;
          unsigned uv = kpx[rt][mt][jp];
          kpT[frl*72 + rt*16+m16]     = (unsigned short)uv;
          kpT[(frl+1)*72 + rt*16+m16] = (unsigned short)(uv>>16);
        }
  }
  __syncthreads();
#pragma unroll
  for (int h=0; h<2; ++h) {
    if (h == 1) {
      __syncthreads();
      if ((w>>1) == 1) {
#pragma unroll
        for (int rt=0;rt<4;++rt)
#pragma unroll
          for (int mt=0;mt<4;++mt)
#pragma unroll
            for (int jp=0;jp<2;++jp){
              int frl = (w&1)*64 + mt*16 + q4*4 + jp*2;
              unsigned uv = kpx[rt][mt][jp];
              kpT[frl*72 + rt*16+m16]     = (unsigned short)uv;
              kpT[(frl+1)*72 + rt*16+m16] = (unsigned short)(uv>>16);
            }
      }
      __syncthreads();
    }
    f32x4 c2a[5][2];
#pragma unroll
    for (int ct=0;ct<5;++ct)
#pragma unroll
      for (int p=0;p<2;++p) c2a[ct][p] = (f32x4){0.f,0.f,0.f,0.f};
#pragma unroll
    for (int kk=0;kk<2;++kk){
      bf16x8 av[5];
#pragma unroll
      for (int ct=0;ct<5;++ct)
        av[ct] = *(const bf16x8*)&C_[(ct*16+m16)*72 + kk*32 + q4*8];
#pragma unroll
      for (int p=0;p<2;++p){
        int mtl = w*2 + p;
        bf16x8 bv = *(const bf16x8*)&kpT[(mtl*16+m16)*72 + kk*32 + q4*8];
#pragma unroll
        for (int ct=0;ct<5;++ct)
          c2a[ct][p] = MFMA(av[ct], bv, c2a[ct][p]);
      }
    }
    // store in B-frag-packed layout: flat = kk*512 + c16*32 + q4m*8 + e  (m = kk*32+q4m*8+e)
#pragma unroll
    for (int ct=0;ct<5;++ct)
#pragma unroll
      for (int p=0;p<2;++p){
        int mtg = h*8 + w*2 + p;
        int mrow = mtg*16 + m16;
        int fb = (mrow>>5)*512 + ((mrow>>3)&3)*8 + (mrow&7);
        unsigned short* dst = kvxP + (size_t)(ch*5+ct)*4096 + fb + (q4*4)*32;
#pragma unroll
        for (int j=0;j<4;++j)
          dst[j*32] = f2b(c2a[ct][p][j]);
      }
    if (h == 0) __syncthreads();
  }
  gbar(bar + 1);   // ============ SYNC 2 ============

  // ================= scan: exclusive prefix over 32 chunks =================
  if (ch < 320) {
    const int qtr = ch & 3, ct = (ch>>2)%5, bh = ch/20;
    const int fbase = qtr*1024 + t*4;
    const bool isEps = (ct==4) && (((fbase>>5)&15) == 1);
    float carry0=0.f, carry1=0.f, carry2=0.f, carry3=0.f;
    const size_t stride = (size_t)5*4096;
    size_t base = ((size_t)(bh*32)*5 + ct)*4096 + fbase;
#pragma unroll 4
    for (int chl=0; chl<32; ++chl){
      unsigned s0, s1;
      if (isEps) { unsigned ee = pk2f(1e-6f,1e-6f); s0 = ee; s1 = ee; }
      else { s0 = pk2f(carry0,carry1); s1 = pk2f(carry2,carry3); }
      *(uint2*)(sxP + base) = make_uint2(s0, s1);
      uint2 raw = *(const uint2*)(kvxP + base);
      carry0 += b2f((unsigned short)(raw.x));
      carry1 += b2f((unsigned short)(raw.x>>16));
      carry2 += b2f((unsigned short)(raw.y));
      carry3 += b2f((unsigned short)(raw.y>>16));
      base += stride;
    }
  }
  gbar(bar + 2);   // ============ SYNC 3 ============

  // ================= out: A=Q'K'^T -> P ; O = Q'Sx + P*Vext =================
  f32x4 accA[4], accO[5];
#pragma unroll
  for (int i=0;i<4;++i) accA[i] = (f32x4){0.f,0.f,0.f,0.f};
#pragma unroll
  for (int i=0;i<5;++i) accO[i] = (f32x4){0.f,0.f,0.f,0.f};
  const unsigned short* sxp = sxP + (size_t)ch*5*4096 + m16*32 + q4*8;
#pragma unroll
  for (int kk=0;kk<8;++kk){
    bf16x8 a = aq[kk];
#pragma unroll
    for (int st=0;st<4;++st){
      bf16x8 bfr = *(const bf16x8*)&kpS[(st*16+m16)*264 + kk*32 + q4*8];
      accA[st] = MFMA(a, bfr, accA[st]);
    }
#pragma unroll
    for (int ct=0;ct<5;++ct){
      bf16x8 bfr = *(const bf16x8*)(sxp + ct*4096 + kk*512);
      accO[ct] = MFMA(a, bfr, accO[ct]);
    }
  }
  // causal mask -> P (wave-local rows; Bu free since sync2)
  unsigned short* P = Bu;
#pragma unroll
  for (int st=0;st<4;++st)
#pragma unroll
    for (int j=0;j<4;++j){
      int rr = r0 + q4*4 + j;
      int cc = st*16 + m16;
      P[rr*72 + cc] = f2b((cc<=rr) ? accA[st][j] : 0.f);
    }
#pragma unroll
  for (int k2=0;k2<2;++k2){
    bf16x8 aP = *(const bf16x8*)&P[(r0+m16)*72 + k2*32 + q4*8];
#pragma unroll
    for (int ct=0;ct<5;++ct){
      bf16x8 bfr = *(const bf16x8*)&C_[(ct*16+m16)*72 + k2*32 + q4*8];
      accO[ct] = MFMA(aP, bfr, accO[ct]);
    }
  }
  __syncthreads();   // all kpS reads done -> oT overlay of A_
  float* oT = (float*)A_;
#pragma unroll
  for (int j=0;j<4;++j){
    float d64 = __shfl(accO[4][j], (lane & 48));
    float d65 = __shfl(accO[4][j], (lane & 48) | 1);
    float dinv = 1.f/(d64+d65);
    int rr = r0 + q4*4 + j;
#pragma unroll
    for (int ct=0;ct<4;++ct)
      oT[rr*68 + ct*16 + m16] = accO[ct][j]*dinv;
  }
  __syncthreads();
#pragma unroll
  for (int i=0;i<4;++i){ int flat=i*1024+t*4; int r=flat>>6, c2=flat&63;
    *(float4*)(out_g + (size_t)row0*64 + flat) = *(const float4*)&oT[r*68+c2]; }
}

extern "C" void kernel_launch(void* const* d_in, const int* in_sizes, int n_in,
                              void* d_out, int out_size, void* d_ws, size_t ws_size,
                              hipStream_t stream)
{
  (void)in_sizes; (void)n_in; (void)out_size; (void)ws_size;
  const float* q    = (const float*)d_in[0];
  const float* k    = (const float*)d_in[1];
  const float* v    = (const float*)d_in[2];
  const float* proj = (const float*)d_in[3];
  float* out = (float*)d_out;

  char* p8 = (char*)d_ws;
  unsigned short* kvxP = (unsigned short*)p8; p8 += (size_t)NCH_*5*4096*2;  // 20.97 MB
  unsigned short* sxP  = (unsigned short*)p8; p8 += (size_t)NCH_*5*4096*2;  // 20.97 MB
  float* blockmax = (float*)p8;  p8 += NCH_*sizeof(float);
  unsigned* bar = (unsigned*)p8;

  init_kernel <<<dim3(1),    dim3(64),  0, stream>>>(bar);
  fused_kernel<<<dim3(NCH_), dim3(256), 0, stream>>>(q, k, v, proj, blockmax,
                                                     kvxP, sxP, out, bar);
}

// Round 9
// 214.531 us; speedup vs baseline: 1.5318x; 1.5318x over previous
//
#include <hip/hip_runtime.h>
#include <hip/hip_bf16.h>
#include <cstddef>

typedef __attribute__((ext_vector_type(8))) short bf16x8;
typedef __attribute__((ext_vector_type(4))) float f32x4;

#define NCH_ 512
#define NRM_ 0.35355339059327373f  // 64^-0.25
#define RATIO_ 0.0625f             // 256^-0.5
#define MFMA(a,b,c) __builtin_amdgcn_mfma_f32_16x16x32_bf16((a),(b),(c),0,0,0)

__device__ __forceinline__ unsigned short f2b(float f) {
  unsigned u = __float_as_uint(f);
  u += 0x7FFFu + ((u >> 16) & 1u);
  return (unsigned short)(u >> 16);
}
__device__ __forceinline__ float b2f(unsigned short h) {
  return __uint_as_float(((unsigned)h) << 16);
}
__device__ __forceinline__ unsigned pk2f(float a, float b) {
  union { __hip_bfloat162 h; unsigned u; } cv;
  cv.h = __float22bfloat162_rn(make_float2(a, b));
  return cv.u;
}
__device__ __forceinline__ bf16x8 cvt8(float4 a, float4 b) {
  union { bf16x8 v; unsigned u[4]; } r;
  r.u[0]=pk2f(a.x,a.y); r.u[1]=pk2f(a.z,a.w);
  r.u[2]=pk2f(b.x,b.y); r.u[3]=pk2f(b.z,b.w);
  return r.v;
}
__device__ __forceinline__ float sumsq4(float4 a){ return a.x*a.x+a.y*a.y+a.z*a.z+a.w*a.w; }
__device__ __forceinline__ float4 sc4(float4 f){ return make_float4(NRM_*f.x,NRM_*f.y,NRM_*f.z,NRM_*f.w); }

// Split barrier. Arrive: one release fence (wbl2) + relaxed add.
// Wait: RELAXED spin (no per-poll invalidate!) + one acquire fence on exit.
__device__ __forceinline__ void gbar_arrive(unsigned* bar) {
  __syncthreads();   // all block stores drained (compiler emits vmcnt(0) before s_barrier)
  if (threadIdx.x == 0) {
    __builtin_amdgcn_fence(__ATOMIC_RELEASE, "agent");
    __hip_atomic_fetch_add(bar, 1u, __ATOMIC_RELAXED, __HIP_MEMORY_SCOPE_AGENT);
  }
}
__device__ __forceinline__ void gbar_wait(unsigned* bar, unsigned n) {
  if (threadIdx.x == 0) {
    while (__hip_atomic_load(bar, __ATOMIC_RELAXED, __HIP_MEMORY_SCOPE_AGENT) < n)
      __builtin_amdgcn_s_sleep(8);
    __builtin_amdgcn_fence(__ATOMIC_ACQUIRE, "agent");
  }
  __syncthreads();
}

__global__ void init_kernel(unsigned* bar) {
  if (threadIdx.x < 8) bar[threadIdx.x] = 0u;
}

// One persistent block per 64-row chunk. LDS regions:
//  A_ 36,864B : proj u16[256][72] -> qS/kpS u16[64][264] -> oT f32[64][68]
//  Bf 18,432B : x f32[64][72] -> kpT u16[128][72] -> P u16[64][72]
//  C_ 11,520B : vext u16[80][72] (alive whole kernel)
//  rmS 1KB + kmS
__global__ __launch_bounds__(256, 2) void fused_kernel(
    const float* __restrict__ qg, const float* __restrict__ kg,
    const float* __restrict__ vg, const float* __restrict__ projg,
    float* __restrict__ blockmax, unsigned short* __restrict__ kvxP,
    unsigned short* __restrict__ sxP, float* __restrict__ out_g,
    unsigned* __restrict__ bar)
{
  __shared__ __align__(16) unsigned char lds[36864 + 18432 + 11520 + 1024 + 16];
  unsigned short* A_  = (unsigned short*)lds;
  float*          Bf  = (float*)(lds + 36864);
  unsigned short* Bu  = (unsigned short*)Bf;
  unsigned short* C_  = (unsigned short*)(lds + 36864 + 18432);
  float*          rmS = (float*)(lds + 36864 + 18432 + 11520);   // [4][64]
  float*          kmS = rmS + 256;

  const int t = threadIdx.x, ch = blockIdx.x;
  const int row0 = ch*64;
  const int lane=t&63, m16=lane&15, q4=lane>>4, w=t>>6;
  const int f0 = w*64, r0 = w*16;

  // ================= phase A: stage proj + k-x + vext =================
#pragma unroll
  for (int i=0;i<8;++i){ int flat=i*2048+t*8; int f=flat>>6, d2=flat&63;
    float4 p0 = *(const float4*)(projg+flat);
    float4 p1 = *(const float4*)(projg+flat+4);
    *(uint4*)&A_[f*72+d2] = make_uint4(pk2f(p0.x,p0.y),pk2f(p0.z,p0.w),
                                       pk2f(p1.x,p1.y),pk2f(p1.z,p1.w)); }
  {
    const float* xg2 = kg + (size_t)row0*64;
#pragma unroll
    for (int i=0;i<4;++i){ int flat=i*1024+t*4; int r=flat>>6, d2=flat&63;
      *(float4*)&Bf[r*72+d2] = *(const float4*)(xg2+flat); }
  }
  {
    int c = t&63, sq_ = t>>6;
#pragma unroll
    for (int i=0;i<16;++i)
      C_[c*72 + sq_*16 + i] = f2b(vg[((size_t)row0 + sq_*16 + i)*64 + c]);
    int cc = 64 + (t>>4), s4 = (t&15)*4;
    unsigned short hv = (cc==64) ? (unsigned short)0x3F80 : (unsigned short)0;
    unsigned pv = (unsigned)hv | ((unsigned)hv<<16);
    *(uint2*)&C_[cc*72 + s4] = make_uint2(pv, pv);
  }
  __syncthreads();

  // ---- k diag + frags + GEMM (acc held across grid barrier) ----
  float kdiag4[4];
  f32x4 kacc[4][4];
  {
    bf16x8 kb[4][2];
#pragma unroll
    for (int rt=0;rt<4;++rt){
      const float* xr = &Bf[(rt*16+m16)*72 + q4*8];
      float4 x0=*(const float4*)(xr), x1=*(const float4*)(xr+4);
      float4 x2=*(const float4*)(xr+32), x3=*(const float4*)(xr+36);
      float sq = sumsq4(x0)+sumsq4(x1)+sumsq4(x2)+sumsq4(x3);
      sq += __shfl_xor(sq,16); sq += __shfl_xor(sq,32);
      kdiag4[rt] = 0.0625f*sq;
      kb[rt][0]=cvt8(sc4(x0),sc4(x1)); kb[rt][1]=cvt8(sc4(x2),sc4(x3));
    }
#pragma unroll
    for (int rt=0;rt<4;++rt)
#pragma unroll
      for (int mt=0;mt<4;++mt) kacc[rt][mt] = (f32x4){0.f,0.f,0.f,0.f};
#pragma unroll
    for (int kk=0;kk<2;++kk)
#pragma unroll
      for (int mt=0;mt<4;++mt){
        bf16x8 a = *(const bf16x8*)&A_[(f0+mt*16+m16)*72 + kk*32 + q4*8];
#pragma unroll
        for (int rt=0;rt<4;++rt)
          kacc[rt][mt] = MFMA(a, kb[rt][kk], kacc[rt][mt]);
      }
  }
  // ---- k chunk max -> blockmax, publish EARLY (overlap wait with q work) ----
  {
    float mx = kacc[0][0][0];
#pragma unroll
    for (int rt=0;rt<4;++rt)
#pragma unroll
      for (int mt=0;mt<4;++mt)
#pragma unroll
        for (int j=0;j<4;++j) mx = fmaxf(mx, kacc[rt][mt][j]);
#pragma unroll
    for (int off=1; off<64; off<<=1) mx = fmaxf(mx, __shfl_xor(mx, off));
    if (lane == 0) rmS[w*64] = mx;
    __syncthreads();
    if (t == 0)
      blockmax[ch] = fmaxf(fmaxf(rmS[0],rmS[64]),fmaxf(rmS[128],rmS[192]));
  }
  gbar_arrive(bar + 0);   // ==== SYNC 1 arrive (k-x reads of Bf also done) ====

  // ---- q: stage, GEMM, rowmax, exp -> qS, A-frags to regs (overlaps barrier) ----
  {
    const float* xg2 = qg + (size_t)row0*64;
#pragma unroll
    for (int i=0;i<4;++i){ int flat=i*1024+t*4; int r=flat>>6, d2=flat&63;
      *(float4*)&Bf[r*72+d2] = *(const float4*)(xg2+flat); }
  }
  __syncthreads();
  bf16x8 aq[8];
  {
    float qdiag4[4];
    f32x4 qacc[4][4];
    bf16x8 qb[4][2];
#pragma unroll
    for (int rt=0;rt<4;++rt){
      const float* xr = &Bf[(rt*16+m16)*72 + q4*8];
      float4 x0=*(const float4*)(xr), x1=*(const float4*)(xr+4);
      float4 x2=*(const float4*)(xr+32), x3=*(const float4*)(xr+36);
      float sq = sumsq4(x0)+sumsq4(x1)+sumsq4(x2)+sumsq4(x3);
      sq += __shfl_xor(sq,16); sq += __shfl_xor(sq,32);
      qdiag4[rt] = 0.0625f*sq;
      qb[rt][0]=cvt8(sc4(x0),sc4(x1)); qb[rt][1]=cvt8(sc4(x2),sc4(x3));
    }
#pragma unroll
    for (int rt=0;rt<4;++rt)
#pragma unroll
      for (int mt=0;mt<4;++mt) qacc[rt][mt] = (f32x4){0.f,0.f,0.f,0.f};
#pragma unroll
    for (int kk=0;kk<2;++kk)
#pragma unroll
      for (int mt=0;mt<4;++mt){
        bf16x8 a = *(const bf16x8*)&A_[(f0+mt*16+m16)*72 + kk*32 + q4*8];
#pragma unroll
        for (int rt=0;rt<4;++rt)
          qacc[rt][mt] = MFMA(a, qb[rt][kk], qacc[rt][mt]);
      }
#pragma unroll
    for (int rt=0;rt<4;++rt){
      float p = qacc[rt][0][0];
#pragma unroll
      for (int mt=0;mt<4;++mt)
#pragma unroll
        for (int j=0;j<4;++j) p = fmaxf(p, qacc[rt][mt][j]);
      p = fmaxf(p, __shfl_xor(p,16)); p = fmaxf(p, __shfl_xor(p,32));
      if (q4 == 0) rmS[w*64 + rt*16+m16] = p;
    }
    __syncthreads();   // rmS ready; all proj reads of A_ done
    unsigned short* qS = A_;
#pragma unroll
    for (int rt=0;rt<4;++rt){
      int rr = rt*16+m16;
      float rm = fmaxf(fmaxf(rmS[rr],rmS[64+rr]),fmaxf(rmS[128+rr],rmS[192+rr]));
      float e = qdiag4[rt] + rm;
#pragma unroll
      for (int mt=0;mt<4;++mt){
        float v0 = RATIO_*(__expf(qacc[rt][mt][0]-e)+1e-4f);
        float v1 = RATIO_*(__expf(qacc[rt][mt][1]-e)+1e-4f);
        float v2 = RATIO_*(__expf(qacc[rt][mt][2]-e)+1e-4f);
        float v3 = RATIO_*(__expf(qacc[rt][mt][3]-e)+1e-4f);
        *(uint2*)&qS[rr*264 + f0 + mt*16 + q4*4] = make_uint2(pk2f(v0,v1), pk2f(v2,v3));
      }
    }
    __syncthreads();
#pragma unroll
    for (int kk=0;kk<8;++kk)
      aq[kk] = *(const bf16x8*)&qS[(r0+m16)*264 + kk*32 + q4*8];
  }
  gbar_wait(bar + 0, NCH_);   // ==== SYNC 1 wait ====

  // ================= phase B: k' exp + chunk-sum GEMM =================
  if (t < 32) {
    float bm = blockmax[(ch>>5)*32 + t];
#pragma unroll
    for (int off=16; off>=1; off>>=1) bm = fmaxf(bm, __shfl_xor(bm, off));
    if (t == 0) *kmS = bm;
  }
  __syncthreads();
  const float kmx = *kmS;
  unsigned short* kpS = A_;   // qS dead (aq in regs)
  unsigned short* kpT = Bu;
  unsigned kpx[4][4][2];
#pragma unroll
  for (int rt=0;rt<4;++rt){
    float e = kdiag4[rt] + kmx;
    int rr = rt*16+m16;
#pragma unroll
    for (int mt=0;mt<4;++mt){
      float v0 = RATIO_*(__expf(kacc[rt][mt][0]-e)+1e-4f);
      float v1 = RATIO_*(__expf(kacc[rt][mt][1]-e)+1e-4f);
      float v2 = RATIO_*(__expf(kacc[rt][mt][2]-e)+1e-4f);
      float v3 = RATIO_*(__expf(kacc[rt][mt][3]-e)+1e-4f);
      kpx[rt][mt][0] = pk2f(v0,v1); kpx[rt][mt][1] = pk2f(v2,v3);
      *(uint2*)&kpS[rr*264 + f0 + mt*16 + q4*4] = make_uint2(kpx[rt][mt][0], kpx[rt][mt][1]);
    }
  }
  if ((w>>1) == 0) {   // kpT half 0 (features 0..127)
#pragma unroll
    for (int rt=0;rt<4;++rt)
#pragma unroll
      for (int mt=0;mt<4;++mt)
#pragma unroll
        for (int jp=0;jp<2;++jp){
          int frl = (w&1)*64 + mt*16 + q4*4 + jp*2;
          unsigned uv = kpx[rt][mt][jp];
          kpT[frl*72 + rt*16+m16]     = (unsigned short)uv;
          kpT[(frl+1)*72 + rt*16+m16] = (unsigned short)(uv>>16);
        }
  }
  __syncthreads();
#pragma unroll
  for (int h=0; h<2; ++h) {
    if (h == 1) {
      __syncthreads();
      if ((w>>1) == 1) {
#pragma unroll
        for (int rt=0;rt<4;++rt)
#pragma unroll
          for (int mt=0;mt<4;++mt)
#pragma unroll
            for (int jp=0;jp<2;++jp){
              int frl = (w&1)*64 + mt*16 + q4*4 + jp*2;
              unsigned uv = kpx[rt][mt][jp];
              kpT[frl*72 + rt*16+m16]     = (unsigned short)uv;
              kpT[(frl+1)*72 + rt*16+m16] = (unsigned short)(uv>>16);
            }
      }
      __syncthreads();
    }
    f32x4 c2a[5][2];
#pragma unroll
    for (int ct=0;ct<5;++ct)
#pragma unroll
      for (int p=0;p<2;++p) c2a[ct][p] = (f32x4){0.f,0.f,0.f,0.f};
#pragma unroll
    for (int kk=0;kk<2;++kk){
      bf16x8 av[5];
#pragma unroll
      for (int ct=0;ct<5;++ct)
        av[ct] = *(const bf16x8*)&C_[(ct*16+m16)*72 + kk*32 + q4*8];
#pragma unroll
      for (int p=0;p<2;++p){
        int mtl = w*2 + p;
        bf16x8 bv = *(const bf16x8*)&kpT[(mtl*16+m16)*72 + kk*32 + q4*8];
#pragma unroll
        for (int ct=0;ct<5;++ct)
          c2a[ct][p] = MFMA(av[ct], bv, c2a[ct][p]);
      }
    }
    // store in B-frag-packed layout: flat = kk*512 + c16*32 + q4m*8 + e  (m = kk*32+q4m*8+e)
#pragma unroll
    for (int ct=0;ct<5;++ct)
#pragma unroll
      for (int p=0;p<2;++p){
        int mtg = h*8 + w*2 + p;
        int mrow = mtg*16 + m16;
        int fb = (mrow>>5)*512 + ((mrow>>3)&3)*8 + (mrow&7);
        unsigned short* dst = kvxP + (size_t)(ch*5+ct)*4096 + fb + (q4*4)*32;
#pragma unroll
        for (int j=0;j<4;++j)
          dst[j*32] = f2b(c2a[ct][p][j]);
      }
    if (h == 0) __syncthreads();
  }
  gbar_arrive(bar + 1);   // ==== SYNC 2 arrive ====

  // ---- overlap: accA = Q'K'^T, mask -> P, accO += P*Vext (all LDS-local) ----
  f32x4 accA[4], accO[5];
#pragma unroll
  for (int i=0;i<4;++i) accA[i] = (f32x4){0.f,0.f,0.f,0.f};
#pragma unroll
  for (int i=0;i<5;++i) accO[i] = (f32x4){0.f,0.f,0.f,0.f};
#pragma unroll
  for (int kk=0;kk<8;++kk){
    bf16x8 a = aq[kk];
#pragma unroll
    for (int st=0;st<4;++st){
      bf16x8 bfr = *(const bf16x8*)&kpS[(st*16+m16)*264 + kk*32 + q4*8];
      accA[st] = MFMA(a, bfr, accA[st]);
    }
  }
  unsigned short* P = Bu;   // kpT reads all done (arrive's syncthreads)
#pragma unroll
  for (int st=0;st<4;++st)
#pragma unroll
    for (int j=0;j<4;++j){
      int rr = r0 + q4*4 + j;
      int cc = st*16 + m16;
      P[rr*72 + cc] = f2b((cc<=rr) ? accA[st][j] : 0.f);
    }
#pragma unroll
  for (int k2=0;k2<2;++k2){
    bf16x8 aP = *(const bf16x8*)&P[(r0+m16)*72 + k2*32 + q4*8];
#pragma unroll
    for (int ct=0;ct<5;++ct){
      bf16x8 bfr = *(const bf16x8*)&C_[(ct*16+m16)*72 + k2*32 + q4*8];
      accO[ct] = MFMA(aP, bfr, accO[ct]);
    }
  }

  // ================= scan blocks: wait, prefix, publish =================
  if (ch < 320) {
    gbar_wait(bar + 1, NCH_);   // ==== SYNC 2 wait (scan blocks only) ====
    const int qtr = ch & 3, ct = (ch>>2)%5, bh = ch/20;
    const int fbase = qtr*1024 + t*4;
    const bool isEps = (ct==4) && (((fbase>>5)&15) == 1);
    float carry0=0.f, carry1=0.f, carry2=0.f, carry3=0.f;
    const size_t stride = (size_t)5*4096;
    size_t base = ((size_t)(bh*32)*5 + ct)*4096 + fbase;
#pragma unroll 4
    for (int chl=0; chl<32; ++chl){
      unsigned s0, s1;
      if (isEps) { unsigned ee = pk2f(1e-6f,1e-6f); s0 = ee; s1 = ee; }
      else { s0 = pk2f(carry0,carry1); s1 = pk2f(carry2,carry3); }
      *(uint2*)(sxP + base) = make_uint2(s0, s1);
      uint2 raw = *(const uint2*)(kvxP + base);
      carry0 += b2f((unsigned short)(raw.x));
      carry1 += b2f((unsigned short)(raw.x>>16));
      carry2 += b2f((unsigned short)(raw.y));
      carry3 += b2f((unsigned short)(raw.y>>16));
      base += stride;
    }
    gbar_arrive(bar + 2);
  }
  gbar_wait(bar + 2, 320);   // ==== SYNC 3 wait ====

  // ================= out: accO += Q'*Sx ; den; epilogue =================
  const unsigned short* sxp = sxP + (size_t)ch*5*4096 + m16*32 + q4*8;
#pragma unroll
  for (int kk=0;kk<8;++kk){
    bf16x8 a = aq[kk];
#pragma unroll
    for (int ct=0;ct<5;++ct){
      bf16x8 bfr = *(const bf16x8*)(sxp + ct*4096 + kk*512);
      accO[ct] = MFMA(a, bfr, accO[ct]);
    }
  }
  __syncthreads();   // all kpS reads done -> oT overlay of A_
  float* oT = (float*)A_;
#pragma unroll
  for (int j=0;j<4;++j){
    float d64 = __shfl(accO[4][j], (lane & 48));
    float d65 = __shfl(accO[4][j], (lane & 48) | 1);
    float dinv = 1.f/(d64+d65);
    int rr = r0 + q4*4 + j;
#pragma unroll
    for (int ct=0;ct<4;++ct)
      oT[rr*68 + ct*16 + m16] = accO[ct][j]*dinv;
  }
  __syncthreads();
#pragma unroll
  for (int i=0;i<4;++i){ int flat=i*1024+t*4; int r=flat>>6, c2=flat&63;
    *(float4*)(out_g + (size_t)row0*64 + flat) = *(const float4*)&oT[r*68+c2]; }
}

extern "C" void kernel_launch(void* const* d_in, const int* in_sizes, int n_in,
                              void* d_out, int out_size, void* d_ws, size_t ws_size,
                              hipStream_t stream)
{
  (void)in_sizes; (void)n_in; (void)out_size; (void)ws_size;
  const float* q    = (const float*)d_in[0];
  const float* k    = (const float*)d_in[1];
  const float* v    = (const float*)d_in[2];
  const float* proj = (const float*)d_in[3];
  float* out = (float*)d_out;

  char* p8 = (char*)d_ws;
  unsigned short* kvxP = (unsigned short*)p8; p8 += (size_t)NCH_*5*4096*2;  // 20.97 MB
  unsigned short* sxP  = (unsigned short*)p8; p8 += (size_t)NCH_*5*4096*2;  // 20.97 MB
  float* blockmax = (float*)p8;  p8 += NCH_*sizeof(float);
  unsigned* bar = (unsigned*)p8;

  init_kernel <<<dim3(1),    dim3(64),  0, stream>>>(bar);
  fused_kernel<<<dim3(NCH_), dim3(256), 0, stream>>>(q, k, v, proj, blockmax,
                                                     kvxP, sxP, out, bar);
}

// Round 10
// 150.778 us; speedup vs baseline: 2.1795x; 1.4228x over previous
//
#include <hip/hip_runtime.h>
#include <hip/hip_bf16.h>
#include <cstddef>

typedef __attribute__((ext_vector_type(8))) short bf16x8;
typedef __attribute__((ext_vector_type(4))) float f32x4;

#define NCH_ 512
#define NRM_ 0.35355339059327373f  // 64^-0.25
#define RATIO_ 0.0625f             // 256^-0.5
#define MFMA(a,b,c) __builtin_amdgcn_mfma_f32_16x16x32_bf16((a),(b),(c),0,0,0)

__device__ __forceinline__ unsigned short f2b(float f) {
  unsigned u = __float_as_uint(f);
  u += 0x7FFFu + ((u >> 16) & 1u);
  return (unsigned short)(u >> 16);
}
__device__ __forceinline__ float b2f(unsigned short h) {
  return __uint_as_float(((unsigned)h) << 16);
}
__device__ __forceinline__ unsigned pk2f(float a, float b) {
  union { __hip_bfloat162 h; unsigned u; } cv;
  cv.h = __float22bfloat162_rn(make_float2(a, b));
  return cv.u;
}
__device__ __forceinline__ bf16x8 cvt8(float4 a, float4 b) {
  union { bf16x8 v; unsigned u[4]; } r;
  r.u[0]=pk2f(a.x,a.y); r.u[1]=pk2f(a.z,a.w);
  r.u[2]=pk2f(b.x,b.y); r.u[3]=pk2f(b.z,b.w);
  return r.v;
}
__device__ __forceinline__ float sumsq4(float4 a){ return a.x*a.x+a.y*a.y+a.z*a.z+a.w*a.w; }
__device__ __forceinline__ float4 sc4(float4 f){ return make_float4(NRM_*f.x,NRM_*f.y,NRM_*f.z,NRM_*f.w); }

// K1: blocks 0..511 -> k chunk-max; 512..1023 -> q-features (A-frag-packed out).
// proj/x fragments loaded DIRECTLY from global (L1/L2-hot) -> LDS only 34KB -> 4 blocks/CU.
__global__ __launch_bounds__(256, 4) void feat_all(
    const float* __restrict__ qg, const float* __restrict__ kg,
    const float* __restrict__ projg,
    unsigned short* __restrict__ qpP, float* __restrict__ blockmax)
{
  __shared__ unsigned short qS[64*264];   // 33.8 KB (q-blocks only)
  __shared__ float rmS[4*64];
  const int t=threadIdx.x, bb=blockIdx.x;
  const bool isq = bb >= NCH_;
  const int blk = bb & (NCH_-1);
  const float* x = isq ? qg : kg;
  const int row0 = blk*64;
  const int lane=t&63, m16=lane&15, q4=lane>>4, w=t>>6;
  const int f0 = w*64;

  // x B-frags + diag, straight from global (rows rt*16+m16, cols q4*8 / +32)
  bf16x8 b[4][2]; float diag4[4];
#pragma unroll
  for (int rt=0;rt<4;++rt){
    const float* xr = x + (size_t)(row0 + rt*16 + m16)*64 + q4*8;
    float4 x0=*(const float4*)(xr), x1=*(const float4*)(xr+4);
    float4 x2=*(const float4*)(xr+32), x3=*(const float4*)(xr+36);
    float sq = sumsq4(x0)+sumsq4(x1)+sumsq4(x2)+sumsq4(x3);
    sq += __shfl_xor(sq,16); sq += __shfl_xor(sq,32);
    diag4[rt] = 0.0625f*sq;
    b[rt][0]=cvt8(sc4(x0),sc4(x1)); b[rt][1]=cvt8(sc4(x2),sc4(x3));
  }

  f32x4 acc[4][4];
#pragma unroll
  for (int rt=0;rt<4;++rt)
#pragma unroll
    for (int mt=0;mt<4;++mt) acc[rt][mt] = (f32x4){0.f,0.f,0.f,0.f};
#pragma unroll
  for (int kk=0;kk<2;++kk)
#pragma unroll
    for (int mt=0;mt<4;++mt){
      const float* pp = projg + (size_t)(f0 + mt*16 + m16)*64 + kk*32 + q4*8;
      bf16x8 a = cvt8(*(const float4*)pp, *(const float4*)(pp+4));
#pragma unroll
      for (int rt=0;rt<4;++rt)
        acc[rt][mt] = MFMA(a, b[rt][kk], acc[rt][mt]);
    }

  if (!isq) {
    float mx = acc[0][0][0];
#pragma unroll
    for (int rt=0;rt<4;++rt)
#pragma unroll
      for (int mt=0;mt<4;++mt)
#pragma unroll
        for (int j=0;j<4;++j) mx = fmaxf(mx, acc[rt][mt][j]);
#pragma unroll
    for (int off=1; off<64; off<<=1) mx = fmaxf(mx, __shfl_xor(mx, off));
    if (lane == 0) rmS[w*64] = mx;
    __syncthreads();
    if (t == 0)
      blockmax[blk] = fmaxf(fmaxf(rmS[0],rmS[64]),fmaxf(rmS[128],rmS[192]));
  } else {
#pragma unroll
    for (int rt=0;rt<4;++rt){
      float p = acc[rt][0][0];
#pragma unroll
      for (int mt=0;mt<4;++mt)
#pragma unroll
        for (int j=0;j<4;++j) p = fmaxf(p, acc[rt][mt][j]);
      p = fmaxf(p, __shfl_xor(p,16)); p = fmaxf(p, __shfl_xor(p,32));
      if (q4 == 0) rmS[w*64 + rt*16+m16] = p;
    }
    __syncthreads();
#pragma unroll
    for (int rt=0;rt<4;++rt){
      int rr = rt*16+m16;
      float rm = fmaxf(fmaxf(rmS[rr],rmS[64+rr]),fmaxf(rmS[128+rr],rmS[192+rr]));
      float e = diag4[rt] + rm;
#pragma unroll
      for (int mt=0;mt<4;++mt){
        float v0 = RATIO_*(__expf(acc[rt][mt][0]-e)+1e-4f);
        float v1 = RATIO_*(__expf(acc[rt][mt][1]-e)+1e-4f);
        float v2 = RATIO_*(__expf(acc[rt][mt][2]-e)+1e-4f);
        float v3 = RATIO_*(__expf(acc[rt][mt][3]-e)+1e-4f);
        *(uint2*)&qS[rr*264 + f0 + mt*16 + q4*4] = make_uint2(pk2f(v0,v1), pk2f(v2,v3));
      }
    }
    __syncthreads();
    // A-frag-packed store: [blk][rtile][kk][m16][q4][e8]
#pragma unroll
    for (int i=0;i<8;++i){
      int bidx = i*256 + t;
      int wp = bidx>>9, m16p = (bidx>>2)&15, kkp = (bidx>>6)&7, q4p = bidx&3;
      *(uint4*)(qpP + (size_t)blk*16384 + bidx*8) =
          *(const uint4*)&qS[(wp*16+m16p)*264 + kkp*32 + q4p*8];
    }
  }
}

// K2: k feature GEMM (frags direct from global) + exp -> kpP (A-frag-packed, same as qpP)
// + chunk-sum GEMM via kpT/vext LDS -> kvxP (B-frag-packed).
__global__ __launch_bounds__(256, 2) void kexp_kernel(
    const float* __restrict__ kg, const float* __restrict__ vg,
    const float* __restrict__ projg, const float* __restrict__ blockmax,
    unsigned short* __restrict__ kpP, unsigned short* __restrict__ kvxP)
{
  __shared__ unsigned short kpS[64*264];   // 33.8 KB [s][m]
  __shared__ unsigned short kpT[128*72];   // 18.4 KB [feat-half][s]
  __shared__ unsigned short vext[80*72];   // 11.5 KB [c][s]
  __shared__ float kmS;
  const int t=threadIdx.x, ch=blockIdx.x;
  const int row0 = ch*64;
  const int lane=t&63, m16=lane&15, q4=lane>>4, w=t>>6;
  const int f0 = w*64;

  {  // stage vext
    int c = t&63, sq_ = t>>6;
#pragma unroll
    for (int i=0;i<16;++i)
      vext[c*72 + sq_*16 + i] = f2b(vg[((size_t)row0 + sq_*16 + i)*64 + c]);
    int cc = 64 + (t>>4), s4 = (t&15)*4;
    unsigned short hv = (cc==64) ? (unsigned short)0x3F80 : (unsigned short)0;
    unsigned pv = (unsigned)hv | ((unsigned)hv<<16);
    *(uint2*)&vext[cc*72 + s4] = make_uint2(pv, pv);
  }
  if (t < 32) {
    float bm = blockmax[(ch>>5)*32 + t];
#pragma unroll
    for (int off=16; off>=1; off>>=1) bm = fmaxf(bm, __shfl_xor(bm, off));
    if (t == 0) kmS = bm;
  }

  bf16x8 b[4][2]; float diag4[4];
#pragma unroll
  for (int rt=0;rt<4;++rt){
    const float* xr = kg + (size_t)(row0 + rt*16 + m16)*64 + q4*8;
    float4 x0=*(const float4*)(xr), x1=*(const float4*)(xr+4);
    float4 x2=*(const float4*)(xr+32), x3=*(const float4*)(xr+36);
    float sq = sumsq4(x0)+sumsq4(x1)+sumsq4(x2)+sumsq4(x3);
    sq += __shfl_xor(sq,16); sq += __shfl_xor(sq,32);
    diag4[rt] = 0.0625f*sq;
    b[rt][0]=cvt8(sc4(x0),sc4(x1)); b[rt][1]=cvt8(sc4(x2),sc4(x3));
  }
  f32x4 acc[4][4];
#pragma unroll
  for (int rt=0;rt<4;++rt)
#pragma unroll
    for (int mt=0;mt<4;++mt) acc[rt][mt] = (f32x4){0.f,0.f,0.f,0.f};
#pragma unroll
  for (int kk=0;kk<2;++kk)
#pragma unroll
    for (int mt=0;mt<4;++mt){
      const float* pp = projg + (size_t)(f0 + mt*16 + m16)*64 + kk*32 + q4*8;
      bf16x8 a = cvt8(*(const float4*)pp, *(const float4*)(pp+4));
#pragma unroll
      for (int rt=0;rt<4;++rt)
        acc[rt][mt] = MFMA(a, b[rt][kk], acc[rt][mt]);
    }
  __syncthreads();   // vext staged, kmS ready
  const float kmx = kmS;

  unsigned kpx[4][4][2];
#pragma unroll
  for (int rt=0;rt<4;++rt){
    float e = diag4[rt] + kmx;
    int rr = rt*16+m16;
#pragma unroll
    for (int mt=0;mt<4;++mt){
      float v0 = RATIO_*(__expf(acc[rt][mt][0]-e)+1e-4f);
      float v1 = RATIO_*(__expf(acc[rt][mt][1]-e)+1e-4f);
      float v2 = RATIO_*(__expf(acc[rt][mt][2]-e)+1e-4f);
      float v3 = RATIO_*(__expf(acc[rt][mt][3]-e)+1e-4f);
      kpx[rt][mt][0] = pk2f(v0,v1); kpx[rt][mt][1] = pk2f(v2,v3);
      *(uint2*)&kpS[rr*264 + f0 + mt*16 + q4*4] = make_uint2(kpx[rt][mt][0], kpx[rt][mt][1]);
    }
  }
  if ((w>>1) == 0) {   // kpT half 0 (features 0..127)
#pragma unroll
    for (int rt=0;rt<4;++rt)
#pragma unroll
      for (int mt=0;mt<4;++mt)
#pragma unroll
        for (int jp=0;jp<2;++jp){
          int frl = (w&1)*64 + mt*16 + q4*4 + jp*2;
          unsigned uv = kpx[rt][mt][jp];
          kpT[frl*72 + rt*16+m16]     = (unsigned short)uv;
          kpT[(frl+1)*72 + rt*16+m16] = (unsigned short)(uv>>16);
        }
  }
  __syncthreads();
  // kpP store, A-frag-packed (identical structure to qpP)
#pragma unroll
  for (int i=0;i<8;++i){
    int bidx = i*256 + t;
    int wp = bidx>>9, m16p = (bidx>>2)&15, kkp = (bidx>>6)&7, q4p = bidx&3;
    *(uint4*)(kpP + (size_t)ch*16384 + bidx*8) =
        *(const uint4*)&kpS[(wp*16+m16p)*264 + kkp*32 + q4p*8];
  }
  // chunk-sum GEMM halves
#pragma unroll
  for (int h=0; h<2; ++h) {
    if (h == 1) {
      __syncthreads();
      if ((w>>1) == 1) {
#pragma unroll
        for (int rt=0;rt<4;++rt)
#pragma unroll
          for (int mt=0;mt<4;++mt)
#pragma unroll
            for (int jp=0;jp<2;++jp){
              int frl = (w&1)*64 + mt*16 + q4*4 + jp*2;
              unsigned uv = kpx[rt][mt][jp];
              kpT[frl*72 + rt*16+m16]     = (unsigned short)uv;
              kpT[(frl+1)*72 + rt*16+m16] = (unsigned short)(uv>>16);
            }
      }
      __syncthreads();
    }
    f32x4 c2a[5][2];
#pragma unroll
    for (int ct=0;ct<5;++ct)
#pragma unroll
      for (int p=0;p<2;++p) c2a[ct][p] = (f32x4){0.f,0.f,0.f,0.f};
#pragma unroll
    for (int kk=0;kk<2;++kk){
      bf16x8 av[5];
#pragma unroll
      for (int ct=0;ct<5;++ct)
        av[ct] = *(const bf16x8*)&vext[(ct*16+m16)*72 + kk*32 + q4*8];
#pragma unroll
      for (int p=0;p<2;++p){
        int mtl = w*2 + p;
        bf16x8 bv = *(const bf16x8*)&kpT[(mtl*16+m16)*72 + kk*32 + q4*8];
#pragma unroll
        for (int ct=0;ct<5;++ct)
          c2a[ct][p] = MFMA(av[ct], bv, c2a[ct][p]);
      }
    }
    // kvxP B-frag-packed: fb = kk*512 + c16*32 + q4m*8 + e
#pragma unroll
    for (int ct=0;ct<5;++ct)
#pragma unroll
      for (int p=0;p<2;++p){
        int mtg = h*8 + w*2 + p;
        int mrow = mtg*16 + m16;
        int fb = (mrow>>5)*512 + ((mrow>>3)&3)*8 + (mrow&7);
        unsigned short* dst = kvxP + (size_t)(ch*5+ct)*4096 + fb + (q4*4)*32;
#pragma unroll
        for (int j=0;j<4;++j)
          dst[j*32] = f2b(c2a[ct][p][j]);
      }
    if (h == 0) __syncthreads();
  }
}

// K3: exclusive prefix over 32 chunks (coalesced packed->packed, register carry).
__global__ __launch_bounds__(256, 4) void scan_kernel(
    const unsigned short* __restrict__ kvxP, unsigned short* __restrict__ sxP)
{
  const int t = threadIdx.x, bid = blockIdx.x;   // 0..319
  const int qtr = bid & 3, ct = (bid>>2)%5, bh = bid/20;
  const int fbase = qtr*1024 + t*4;
  const bool isEps = (ct==4) && (((fbase>>5)&15) == 1);
  float carry0=0.f, carry1=0.f, carry2=0.f, carry3=0.f;
  const size_t stride = (size_t)5*4096;
  size_t base = ((size_t)(bh*32)*5 + ct)*4096 + fbase;
#pragma unroll 4
  for (int chl=0; chl<32; ++chl){
    unsigned s0, s1;
    if (isEps) { unsigned ee = pk2f(1e-6f,1e-6f); s0 = ee; s1 = ee; }
    else { s0 = pk2f(carry0,carry1); s1 = pk2f(carry2,carry3); }
    *(uint2*)(sxP + base) = make_uint2(s0, s1);
    uint2 raw = *(const uint2*)(kvxP + base);
    carry0 += b2f((unsigned short)(raw.x));
    carry1 += b2f((unsigned short)(raw.x>>16));
    carry2 += b2f((unsigned short)(raw.y));
    carry3 += b2f((unsigned short)(raw.y>>16));
    base += stride;
  }
}

// K4: all fragments direct from global (qpP A-frags; kpP/sxP B-frags).
// LDS only vext + P + oT overlay (~21KB) -> 4 blocks/CU.
__global__ __launch_bounds__(256, 4) void out_kernel(
    const unsigned short* __restrict__ qpP, const unsigned short* __restrict__ kpP,
    const unsigned short* __restrict__ sxP, const float* __restrict__ vg,
    float* __restrict__ out_g)
{
  __shared__ __align__(16) unsigned char ldsb[80*72*2 + 64*72*2];  // 20.7 KB
  unsigned short* vx = (unsigned short*)ldsb;              // [80][72]
  unsigned short* P  = (unsigned short*)(ldsb + 80*72*2);  // [64][72]
  float* oT = (float*)ldsb;                                // overlay: [64][68] f32
  const int t=threadIdx.x, ch=blockIdx.x;
  const int row0 = ch*64;
  const int lane=t&63, m16=lane&15, q4=lane>>4, w=t>>6;
  const int r0 = w*16;

  {  // stage vext
    int c = t&63, sq_ = t>>6;
#pragma unroll
    for (int i=0;i<16;++i)
      vx[c*72 + sq_*16 + i] = f2b(vg[((size_t)row0 + sq_*16 + i)*64 + c]);
    int cc = 64 + (t>>4), s4 = (t&15)*4;
    unsigned short hv = (cc==64) ? (unsigned short)0x3F80 : (unsigned short)0;
    unsigned pv = (unsigned)hv | ((unsigned)hv<<16);
    *(uint2*)&vx[cc*72 + s4] = make_uint2(pv, pv);
  }

  f32x4 accA[4], accO[5];
#pragma unroll
  for (int i=0;i<4;++i) accA[i] = (f32x4){0.f,0.f,0.f,0.f};
#pragma unroll
  for (int i=0;i<5;++i) accO[i] = (f32x4){0.f,0.f,0.f,0.f};
  const unsigned short* qpw = qpP + (size_t)ch*16384 + (size_t)w*4096 + m16*32 + q4*8;
  const unsigned short* kpb = kpP + (size_t)ch*16384 + m16*32 + q4*8;
  const unsigned short* sxb = sxP + (size_t)ch*5*4096 + m16*32 + q4*8;
#pragma unroll
  for (int kk=0;kk<8;++kk){
    bf16x8 a = *(const bf16x8*)(qpw + kk*512);
#pragma unroll
    for (int st=0;st<4;++st)
      accA[st] = MFMA(a, *(const bf16x8*)(kpb + (size_t)st*4096 + kk*512), accA[st]);
#pragma unroll
    for (int ct=0;ct<5;++ct)
      accO[ct] = MFMA(a, *(const bf16x8*)(sxb + (size_t)ct*4096 + kk*512), accO[ct]);
  }
  __syncthreads();   // vext staged (P region untouched until now)

  // causal mask -> P (wave-local rows)
#pragma unroll
  for (int st=0;st<4;++st)
#pragma unroll
    for (int j=0;j<4;++j){
      int rr = r0 + q4*4 + j;
      int cc = st*16 + m16;
      P[rr*72 + cc] = f2b((cc<=rr) ? accA[st][j] : 0.f);
    }
#pragma unroll
  for (int k2=0;k2<2;++k2){
    bf16x8 aP = *(const bf16x8*)&P[(r0+m16)*72 + k2*32 + q4*8];
#pragma unroll
    for (int ct=0;ct<5;++ct){
      bf16x8 bfr = *(const bf16x8*)&vx[(ct*16+m16)*72 + k2*32 + q4*8];
      accO[ct] = MFMA(aP, bfr, accO[ct]);
    }
  }
  __syncthreads();   // P/vx reads done -> oT overlay safe
#pragma unroll
  for (int j=0;j<4;++j){
    float d64 = __shfl(accO[4][j], (lane & 48));
    float d65 = __shfl(accO[4][j], (lane & 48) | 1);
    float dinv = 1.f/(d64+d65);
    int rr = r0 + q4*4 + j;
#pragma unroll
    for (int ct=0;ct<4;++ct)
      oT[rr*68 + ct*16 + m16] = accO[ct][j]*dinv;
  }
  __syncthreads();
#pragma unroll
  for (int i=0;i<4;++i){ int flat=i*1024+t*4; int r=flat>>6, c2=flat&63;
    *(float4*)(out_g + (size_t)row0*64 + flat) = *(const float4*)&oT[r*68+c2]; }
}

extern "C" void kernel_launch(void* const* d_in, const int* in_sizes, int n_in,
                              void* d_out, int out_size, void* d_ws, size_t ws_size,
                              hipStream_t stream)
{
  (void)in_sizes; (void)n_in; (void)out_size; (void)ws_size;
  const float* q    = (const float*)d_in[0];
  const float* k    = (const float*)d_in[1];
  const float* v    = (const float*)d_in[2];
  const float* proj = (const float*)d_in[3];
  float* out = (float*)d_out;

  char* p8 = (char*)d_ws;
  unsigned short* qpP  = (unsigned short*)p8; p8 += (size_t)NCH_*16384*2;   // 16.78 MB
  unsigned short* kpP  = (unsigned short*)p8; p8 += (size_t)NCH_*16384*2;   // 16.78 MB
  unsigned short* kvxP = (unsigned short*)p8; p8 += (size_t)NCH_*5*4096*2;  // 20.97 MB
  unsigned short* sxP  = (unsigned short*)p8; p8 += (size_t)NCH_*5*4096*2;  // 20.97 MB
  float* blockmax = (float*)p8;

  feat_all   <<<dim3(2*NCH_), dim3(256), 0, stream>>>(q, k, proj, qpP, blockmax);
  kexp_kernel<<<dim3(NCH_),   dim3(256), 0, stream>>>(k, v, proj, blockmax, kpP, kvxP);
  scan_kernel<<<dim3(320),    dim3(256), 0, stream>>>(kvxP, sxP);
  out_kernel <<<dim3(NCH_),   dim3(256), 0, stream>>>(qpP, kpP, sxP, v, out);
}

// Round 11
// 130.650 us; speedup vs baseline: 2.5153x; 1.1541x over previous
//
#include <hip/hip_runtime.h>
#include <hip/hip_bf16.h>
#include <cstddef>

typedef __attribute__((ext_vector_type(8))) short bf16x8;
typedef __attribute__((ext_vector_type(4))) float f32x4;

#define NCH_ 512
#define NRM_ 0.35355339059327373f  // 64^-0.25
#define RATIO_ 0.0625f             // 256^-0.5
#define MFMA(a,b,c) __builtin_amdgcn_mfma_f32_16x16x32_bf16((a),(b),(c),0,0,0)

__device__ __forceinline__ unsigned short f2b(float f) {
  unsigned u = __float_as_uint(f);
  u += 0x7FFFu + ((u >> 16) & 1u);
  return (unsigned short)(u >> 16);
}
__device__ __forceinline__ float b2f(unsigned short h) {
  return __uint_as_float(((unsigned)h) << 16);
}
__device__ __forceinline__ unsigned pk2f(float a, float b) {
  union { __hip_bfloat162 h; unsigned u; } cv;
  cv.h = __float22bfloat162_rn(make_float2(a, b));
  return cv.u;
}
__device__ __forceinline__ bf16x8 cvt8(float4 a, float4 b) {
  union { bf16x8 v; unsigned u[4]; } r;
  r.u[0]=pk2f(a.x,a.y); r.u[1]=pk2f(a.z,a.w);
  r.u[2]=pk2f(b.x,b.y); r.u[3]=pk2f(b.z,b.w);
  return r.v;
}
__device__ __forceinline__ float sumsq4(float4 a){ return a.x*a.x+a.y*a.y+a.z*a.z+a.w*a.w; }
__device__ __forceinline__ float4 sc4(float4 f){ return make_float4(NRM_*f.x,NRM_*f.y,NRM_*f.z,NRM_*f.w); }

// K1 (r6): blocks 0..511 -> k chunk-max; 512..1023 -> q-features (A-frag-packed out).
// proj + x staged in LDS coalesced; frag reads from LDS.
__global__ __launch_bounds__(256, 2) void feat_all(
    const float* __restrict__ qg, const float* __restrict__ kg,
    const float* __restrict__ projg,
    unsigned short* __restrict__ qpP, float* __restrict__ blockmax)
{
  __shared__ unsigned short R0[256*72];   // proj bf16 [m][d]; q-blocks overlay qS [64][264]
  __shared__ float xS[64*68];
  __shared__ float rmS[4*64];
  const int t=threadIdx.x, bb=blockIdx.x;
  const bool isq = bb >= NCH_;
  const int blk = bb & (NCH_-1);
  const float* x = isq ? qg : kg;
  const int row0 = blk*64;
  const int lane=t&63, m16=lane&15, q4=lane>>4, w=t>>6;
  const int f0 = w*64;

#pragma unroll
  for (int i=0;i<8;++i){ int flat=i*2048+t*8; int f=flat>>6, d2=flat&63;
    float4 p0 = *(const float4*)(projg+flat);
    float4 p1 = *(const float4*)(projg+flat+4);
    *(uint4*)&R0[f*72+d2] = make_uint4(pk2f(p0.x,p0.y),pk2f(p0.z,p0.w),
                                       pk2f(p1.x,p1.y),pk2f(p1.z,p1.w)); }
  const float* xg = x + (size_t)row0*64;
#pragma unroll
  for (int i=0;i<4;++i){ int flat=i*1024+t*4; int r=flat>>6, d2=flat&63;
    *(float4*)&xS[r*68+d2] = *(const float4*)(xg+flat); }
  __syncthreads();

  bf16x8 b[4][2]; float diag4[4];
#pragma unroll
  for (int rt=0;rt<4;++rt){
    const float* xr = &xS[(rt*16+m16)*68 + q4*8];
    float4 x0=*(const float4*)(xr), x1=*(const float4*)(xr+4);
    float4 x2=*(const float4*)(xr+32), x3=*(const float4*)(xr+36);
    float sq = sumsq4(x0)+sumsq4(x1)+sumsq4(x2)+sumsq4(x3);
    sq += __shfl_xor(sq,16); sq += __shfl_xor(sq,32);
    diag4[rt] = 0.0625f*sq;
    b[rt][0]=cvt8(sc4(x0),sc4(x1)); b[rt][1]=cvt8(sc4(x2),sc4(x3));
  }

  f32x4 acc[4][4];
#pragma unroll
  for (int rt=0;rt<4;++rt)
#pragma unroll
    for (int mt=0;mt<4;++mt) acc[rt][mt] = (f32x4){0.f,0.f,0.f,0.f};
#pragma unroll
  for (int kk=0;kk<2;++kk)
#pragma unroll
    for (int mt=0;mt<4;++mt){
      bf16x8 a = *(const bf16x8*)&R0[(f0+mt*16+m16)*72 + kk*32 + q4*8];
#pragma unroll
      for (int rt=0;rt<4;++rt)
        acc[rt][mt] = MFMA(a, b[rt][kk], acc[rt][mt]);
    }

  if (!isq) {
    float mx = acc[0][0][0];
#pragma unroll
    for (int rt=0;rt<4;++rt)
#pragma unroll
      for (int mt=0;mt<4;++mt)
#pragma unroll
        for (int j=0;j<4;++j) mx = fmaxf(mx, acc[rt][mt][j]);
#pragma unroll
    for (int off=1; off<64; off<<=1) mx = fmaxf(mx, __shfl_xor(mx, off));
    if (lane == 0) rmS[w*64] = mx;
    __syncthreads();
    if (t == 0)
      blockmax[blk] = fmaxf(fmaxf(rmS[0],rmS[64]),fmaxf(rmS[128],rmS[192]));
  } else {
    unsigned short* qS = R0;
#pragma unroll
    for (int rt=0;rt<4;++rt){
      float p = acc[rt][0][0];
#pragma unroll
      for (int mt=0;mt<4;++mt)
#pragma unroll
        for (int j=0;j<4;++j) p = fmaxf(p, acc[rt][mt][j]);
      p = fmaxf(p, __shfl_xor(p,16)); p = fmaxf(p, __shfl_xor(p,32));
      if (q4 == 0) rmS[w*64 + rt*16+m16] = p;
    }
    __syncthreads();   // rmS ready; proj reads done -> overlay safe
#pragma unroll
    for (int rt=0;rt<4;++rt){
      int rr = rt*16+m16;
      float rm = fmaxf(fmaxf(rmS[rr],rmS[64+rr]),fmaxf(rmS[128+rr],rmS[192+rr]));
      float e = diag4[rt] + rm;
#pragma unroll
      for (int mt=0;mt<4;++mt){
        float v0 = RATIO_*(__expf(acc[rt][mt][0]-e)+1e-4f);
        float v1 = RATIO_*(__expf(acc[rt][mt][1]-e)+1e-4f);
        float v2 = RATIO_*(__expf(acc[rt][mt][2]-e)+1e-4f);
        float v3 = RATIO_*(__expf(acc[rt][mt][3]-e)+1e-4f);
        *(uint2*)&qS[rr*264 + f0 + mt*16 + q4*4] = make_uint2(pk2f(v0,v1), pk2f(v2,v3));
      }
    }
    __syncthreads();
    // A-frag-packed store
#pragma unroll
    for (int i=0;i<8;++i){
      int bidx = i*256 + t;
      int wp = bidx>>9, m16p = (bidx>>2)&15, kkp = (bidx>>6)&7, q4p = bidx&3;
      *(uint4*)(qpP + (size_t)blk*16384 + bidx*8) =
          *(const uint4*)&qS[(wp*16+m16p)*264 + kkp*32 + q4p*8];
    }
  }
}

// K2: r6-style LDS staging (proj/x/vext), GEMM, exp; r10-style packed stores:
// kpP A-frag-packed + kvxP B-frag-packed.
__global__ __launch_bounds__(256, 2) void kexp_kernel(
    const float* __restrict__ kg, const float* __restrict__ vg,
    const float* __restrict__ projg, const float* __restrict__ blockmax,
    unsigned short* __restrict__ kpP, unsigned short* __restrict__ kvxP)
{
  __shared__ unsigned short A_[256*72];   // proj -> overlay kpS [64][264]
  __shared__ float B_f[64*72];            // x -> overlay kpT u16[128][72]
  __shared__ unsigned short C_[80*72];    // vext [c][s]
  __shared__ float kmS;
  const int t=threadIdx.x, ch=blockIdx.x;
  const int row0 = ch*64;
  const int lane=t&63, m16=lane&15, q4=lane>>4, w=t>>6;
  const int f0 = w*64;
  unsigned short* kpS = A_;
  unsigned short* kpT = (unsigned short*)B_f;

#pragma unroll
  for (int i=0;i<8;++i){ int flat=i*2048+t*8; int f=flat>>6, d2=flat&63;
    float4 p0 = *(const float4*)(projg+flat);
    float4 p1 = *(const float4*)(projg+flat+4);
    *(uint4*)&A_[f*72+d2] = make_uint4(pk2f(p0.x,p0.y),pk2f(p0.z,p0.w),
                                       pk2f(p1.x,p1.y),pk2f(p1.z,p1.w)); }
  {
    const float* xg = kg + (size_t)row0*64;
#pragma unroll
    for (int i=0;i<4;++i){ int flat=i*1024+t*4; int r=flat>>6, d2=flat&63;
      *(float4*)&B_f[r*72+d2] = *(const float4*)(xg+flat); }
  }
  {  // vext: coalesced v loads, strided u16 LDS writes
    int c = t&63, sq_ = t>>6;
#pragma unroll
    for (int i=0;i<16;++i)
      C_[c*72 + sq_*16 + i] = f2b(vg[((size_t)row0 + sq_*16 + i)*64 + c]);
    int cc = 64 + (t>>4), s4 = (t&15)*4;
    unsigned short hv = (cc==64) ? (unsigned short)0x3F80 : (unsigned short)0;
    unsigned pv = (unsigned)hv | ((unsigned)hv<<16);
    *(uint2*)&C_[cc*72 + s4] = make_uint2(pv, pv);
  }
  if (t < 32) {
    float bm = blockmax[(ch>>5)*32 + t];
#pragma unroll
    for (int off=16; off>=1; off>>=1) bm = fmaxf(bm, __shfl_xor(bm, off));
    if (t == 0) kmS = bm;
  }
  __syncthreads();

  bf16x8 b[4][2]; float diag4[4];
#pragma unroll
  for (int rt=0;rt<4;++rt){
    const float* xr = &B_f[(rt*16+m16)*72 + q4*8];
    float4 x0=*(const float4*)(xr), x1=*(const float4*)(xr+4);
    float4 x2=*(const float4*)(xr+32), x3=*(const float4*)(xr+36);
    float sq = sumsq4(x0)+sumsq4(x1)+sumsq4(x2)+sumsq4(x3);
    sq += __shfl_xor(sq,16); sq += __shfl_xor(sq,32);
    diag4[rt] = 0.0625f*sq;
    b[rt][0]=cvt8(sc4(x0),sc4(x1)); b[rt][1]=cvt8(sc4(x2),sc4(x3));
  }
  const float kmx = kmS;

  f32x4 acc[4][4];
#pragma unroll
  for (int rt=0;rt<4;++rt)
#pragma unroll
    for (int mt=0;mt<4;++mt) acc[rt][mt] = (f32x4){0.f,0.f,0.f,0.f};
#pragma unroll
  for (int kk=0;kk<2;++kk)
#pragma unroll
    for (int mt=0;mt<4;++mt){
      bf16x8 a = *(const bf16x8*)&A_[(f0+mt*16+m16)*72 + kk*32 + q4*8];
#pragma unroll
      for (int rt=0;rt<4;++rt)
        acc[rt][mt] = MFMA(a, b[rt][kk], acc[rt][mt]);
    }
  __syncthreads();   // proj/x LDS reads done -> overlays safe

  unsigned kpx[4][4][2];
#pragma unroll
  for (int rt=0;rt<4;++rt){
    float e = diag4[rt] + kmx;
    int rr = rt*16+m16;
#pragma unroll
    for (int mt=0;mt<4;++mt){
      float v0 = RATIO_*(__expf(acc[rt][mt][0]-e)+1e-4f);
      float v1 = RATIO_*(__expf(acc[rt][mt][1]-e)+1e-4f);
      float v2 = RATIO_*(__expf(acc[rt][mt][2]-e)+1e-4f);
      float v3 = RATIO_*(__expf(acc[rt][mt][3]-e)+1e-4f);
      kpx[rt][mt][0] = pk2f(v0,v1); kpx[rt][mt][1] = pk2f(v2,v3);
      *(uint2*)&kpS[rr*264 + f0 + mt*16 + q4*4] = make_uint2(kpx[rt][mt][0], kpx[rt][mt][1]);
    }
  }
  if ((w>>1) == 0) {   // kpT half 0 (features 0..127)
#pragma unroll
    for (int rt=0;rt<4;++rt)
#pragma unroll
      for (int mt=0;mt<4;++mt)
#pragma unroll
        for (int jp=0;jp<2;++jp){
          int frl = (w&1)*64 + mt*16 + q4*4 + jp*2;
          unsigned uv = kpx[rt][mt][jp];
          kpT[frl*72 + rt*16+m16]     = (unsigned short)uv;
          kpT[(frl+1)*72 + rt*16+m16] = (unsigned short)(uv>>16);
        }
  }
  __syncthreads();
  // kpP store, A-frag-packed (identical structure to qpP)
#pragma unroll
  for (int i=0;i<8;++i){
    int bidx = i*256 + t;
    int wp = bidx>>9, m16p = (bidx>>2)&15, kkp = (bidx>>6)&7, q4p = bidx&3;
    *(uint4*)(kpP + (size_t)ch*16384 + bidx*8) =
        *(const uint4*)&kpS[(wp*16+m16p)*264 + kkp*32 + q4p*8];
  }
  // chunk-sum GEMM halves -> kvxP B-frag-packed
#pragma unroll
  for (int h=0; h<2; ++h) {
    if (h == 1) {
      __syncthreads();
      if ((w>>1) == 1) {
#pragma unroll
        for (int rt=0;rt<4;++rt)
#pragma unroll
          for (int mt=0;mt<4;++mt)
#pragma unroll
            for (int jp=0;jp<2;++jp){
              int frl = (w&1)*64 + mt*16 + q4*4 + jp*2;
              unsigned uv = kpx[rt][mt][jp];
              kpT[frl*72 + rt*16+m16]     = (unsigned short)uv;
              kpT[(frl+1)*72 + rt*16+m16] = (unsigned short)(uv>>16);
            }
      }
      __syncthreads();
    }
    f32x4 c2a[5][2];
#pragma unroll
    for (int ct=0;ct<5;++ct)
#pragma unroll
      for (int p=0;p<2;++p) c2a[ct][p] = (f32x4){0.f,0.f,0.f,0.f};
#pragma unroll
    for (int kk=0;kk<2;++kk){
      bf16x8 av[5];
#pragma unroll
      for (int ct=0;ct<5;++ct)
        av[ct] = *(const bf16x8*)&C_[(ct*16+m16)*72 + kk*32 + q4*8];
#pragma unroll
      for (int p=0;p<2;++p){
        int mtl = w*2 + p;
        bf16x8 bv = *(const bf16x8*)&kpT[(mtl*16+m16)*72 + kk*32 + q4*8];
#pragma unroll
        for (int ct=0;ct<5;++ct)
          c2a[ct][p] = MFMA(av[ct], bv, c2a[ct][p]);
      }
    }
    // B-frag-packed: fb = (m>>5)*512 + ((m>>3)&3)*8 + (m&7), + c16*32
#pragma unroll
    for (int ct=0;ct<5;++ct)
#pragma unroll
      for (int p=0;p<2;++p){
        int mtg = h*8 + w*2 + p;
        int mrow = mtg*16 + m16;
        int fb = (mrow>>5)*512 + ((mrow>>3)&3)*8 + (mrow&7);
        unsigned short* dst = kvxP + (size_t)(ch*5+ct)*4096 + fb + (q4*4)*32;
#pragma unroll
        for (int j=0;j<4;++j)
          dst[j*32] = f2b(c2a[ct][p][j]);
      }
    if (h == 0) __syncthreads();
  }
}

// K3 (r10): exclusive prefix over 32 chunks (coalesced packed->packed, register carry).
__global__ __launch_bounds__(256, 4) void scan_kernel(
    const unsigned short* __restrict__ kvxP, unsigned short* __restrict__ sxP)
{
  const int t = threadIdx.x, bid = blockIdx.x;   // 0..319
  const int qtr = bid & 3, ct = (bid>>2)%5, bh = bid/20;
  const int fbase = qtr*1024 + t*4;
  const bool isEps = (ct==4) && (((fbase>>5)&15) == 1);
  float carry0=0.f, carry1=0.f, carry2=0.f, carry3=0.f;
  const size_t stride = (size_t)5*4096;
  size_t base = ((size_t)(bh*32)*5 + ct)*4096 + fbase;
#pragma unroll 4
  for (int chl=0; chl<32; ++chl){
    unsigned s0, s1;
    if (isEps) { unsigned ee = pk2f(1e-6f,1e-6f); s0 = ee; s1 = ee; }
    else { s0 = pk2f(carry0,carry1); s1 = pk2f(carry2,carry3); }
    *(uint2*)(sxP + base) = make_uint2(s0, s1);
    uint2 raw = *(const uint2*)(kvxP + base);
    carry0 += b2f((unsigned short)(raw.x));
    carry1 += b2f((unsigned short)(raw.x>>16));
    carry2 += b2f((unsigned short)(raw.y));
    carry3 += b2f((unsigned short)(raw.y>>16));
    base += stride;
  }
}

// K4 (r10): all fragments direct from global, contiguous 1KB wave loads.
// LDS only vext + P + oT overlay (~21KB) -> 4 blocks/CU.
__global__ __launch_bounds__(256, 4) void out_kernel(
    const unsigned short* __restrict__ qpP, const unsigned short* __restrict__ kpP,
    const unsigned short* __restrict__ sxP, const float* __restrict__ vg,
    float* __restrict__ out_g)
{
  __shared__ __align__(16) unsigned char ldsb[80*72*2 + 64*72*2];  // 20.7 KB
  unsigned short* vx = (unsigned short*)ldsb;              // [80][72]
  unsigned short* P  = (unsigned short*)(ldsb + 80*72*2);  // [64][72]
  float* oT = (float*)ldsb;                                // overlay: [64][68] f32
  const int t=threadIdx.x, ch=blockIdx.x;
  const int row0 = ch*64;
  const int lane=t&63, m16=lane&15, q4=lane>>4, w=t>>6;
  const int r0 = w*16;

  {  // stage vext
    int c = t&63, sq_ = t>>6;
#pragma unroll
    for (int i=0;i<16;++i)
      vx[c*72 + sq_*16 + i] = f2b(vg[((size_t)row0 + sq_*16 + i)*64 + c]);
    int cc = 64 + (t>>4), s4 = (t&15)*4;
    unsigned short hv = (cc==64) ? (unsigned short)0x3F80 : (unsigned short)0;
    unsigned pv = (unsigned)hv | ((unsigned)hv<<16);
    *(uint2*)&vx[cc*72 + s4] = make_uint2(pv, pv);
  }

  f32x4 accA[4], accO[5];
#pragma unroll
  for (int i=0;i<4;++i) accA[i] = (f32x4){0.f,0.f,0.f,0.f};
#pragma unroll
  for (int i=0;i<5;++i) accO[i] = (f32x4){0.f,0.f,0.f,0.f};
  const unsigned short* qpw = qpP + (size_t)ch*16384 + (size_t)w*4096 + m16*32 + q4*8;
  const unsigned short* kpb = kpP + (size_t)ch*16384 + m16*32 + q4*8;
  const unsigned short* sxb = sxP + (size_t)ch*5*4096 + m16*32 + q4*8;
#pragma unroll
  for (int kk=0;kk<8;++kk){
    bf16x8 a = *(const bf16x8*)(qpw + kk*512);
#pragma unroll
    for (int st=0;st<4;++st)
      accA[st] = MFMA(a, *(const bf16x8*)(kpb + (size_t)st*4096 + kk*512), accA[st]);
#pragma unroll
    for (int ct=0;ct<5;++ct)
      accO[ct] = MFMA(a, *(const bf16x8*)(sxb + (size_t)ct*4096 + kk*512), accO[ct]);
  }
  __syncthreads();   // vext staged (P region untouched until now)

  // causal mask -> P (wave-local rows)
#pragma unroll
  for (int st=0;st<4;++st)
#pragma unroll
    for (int j=0;j<4;++j){
      int rr = r0 + q4*4 + j;
      int cc = st*16 + m16;
      P[rr*72 + cc] = f2b((cc<=rr) ? accA[st][j] : 0.f);
    }
#pragma unroll
  for (int k2=0;k2<2;++k2){
    bf16x8 aP = *(const bf16x8*)&P[(r0+m16)*72 + k2*32 + q4*8];
#pragma unroll
    for (int ct=0;ct<5;++ct){
      bf16x8 bfr = *(const bf16x8*)&vx[(ct*16+m16)*72 + k2*32 + q4*8];
      accO[ct] = MFMA(aP, bfr, accO[ct]);
    }
  }
  __syncthreads();   // P/vx reads done -> oT overlay safe
#pragma unroll
  for (int j=0;j<4;++j){
    float d64 = __shfl(accO[4][j], (lane & 48));
    float d65 = __shfl(accO[4][j], (lane & 48) | 1);
    float dinv = 1.f/(d64+d65);
    int rr = r0 + q4*4 + j;
#pragma unroll
    for (int ct=0;ct<4;++ct)
      oT[rr*68 + ct*16 + m16] = accO[ct][j]*dinv;
  }
  __syncthreads();
#pragma unroll
  for (int i=0;i<4;++i){ int flat=i*1024+t*4; int r=flat>>6, c2=flat&63;
    *(float4*)(out_g + (size_t)row0*64 + flat) = *(const float4*)&oT[r*68+c2]; }
}

extern "C" void kernel_launch(void* const* d_in, const int* in_sizes, int n_in,
                              void* d_out, int out_size, void* d_ws, size_t ws_size,
                              hipStream_t stream)
{
  (void)in_sizes; (void)n_in; (void)out_size; (void)ws_size;
  const float* q    = (const float*)d_in[0];
  const float* k    = (const float*)d_in[1];
  const float* v    = (const float*)d_in[2];
  const float* proj = (const float*)d_in[3];
  float* out = (float*)d_out;

  char* p8 = (char*)d_ws;
  unsigned short* qpP  = (unsigned short*)p8; p8 += (size_t)NCH_*16384*2;   // 16.78 MB
  unsigned short* kpP  = (unsigned short*)p8; p8 += (size_t)NCH_*16384*2;   // 16.78 MB
  unsigned short* kvxP = (unsigned short*)p8; p8 += (size_t)NCH_*5*4096*2;  // 20.97 MB
  unsigned short* sxP  = (unsigned short*)p8; p8 += (size_t)NCH_*5*4096*2;  // 20.97 MB
  float* blockmax = (float*)p8;

  feat_all   <<<dim3(2*NCH_), dim3(256), 0, stream>>>(q, k, proj, qpP, blockmax);
  kexp_kernel<<<dim3(NCH_),   dim3(256), 0, stream>>>(k, v, proj, blockmax, kpP, kvxP);
  scan_kernel<<<dim3(320),    dim3(256), 0, stream>>>(kvxP, sxP);
  out_kernel <<<dim3(NCH_),   dim3(256), 0, stream>>>(qpP, kpP, sxP, v, out);
}

// Round 12
// 130.519 us; speedup vs baseline: 2.5178x; 1.0010x over previous
//
#include <hip/hip_runtime.h>
#include <hip/hip_bf16.h>
#include <cstddef>

typedef __attribute__((ext_vector_type(8))) short bf16x8;
typedef __attribute__((ext_vector_type(4))) float f32x4;

#define NCH_ 512
#define NRM_ 0.35355339059327373f  // 64^-0.25
#define RATIO_ 0.0625f             // 256^-0.5
#define MFMA(a,b,c) __builtin_amdgcn_mfma_f32_16x16x32_bf16((a),(b),(c),0,0,0)

__device__ __forceinline__ unsigned short f2b(float f) {
  unsigned u = __float_as_uint(f);
  u += 0x7FFFu + ((u >> 16) & 1u);
  return (unsigned short)(u >> 16);
}
__device__ __forceinline__ float b2f(unsigned short h) {
  return __uint_as_float(((unsigned)h) << 16);
}
__device__ __forceinline__ unsigned pk2f(float a, float b) {
  union { __hip_bfloat162 h; unsigned u; } cv;
  cv.h = __float22bfloat162_rn(make_float2(a, b));
  return cv.u;
}
__device__ __forceinline__ float sumsq4(float4 a){ return a.x*a.x+a.y*a.y+a.z*a.z+a.w*a.w; }

// K1: blocks 0..511 -> k chunk-max; 512..1023 -> q-features (A-frag-packed out).
// x staged as scaled bf16 (9.2KB) with diag computed during staging -> LDS 47.4KB -> 3 blocks/CU.
__global__ __launch_bounds__(256, 3) void feat_all(
    const float* __restrict__ qg, const float* __restrict__ kg,
    const float* __restrict__ projg,
    unsigned short* __restrict__ qpP, float* __restrict__ blockmax)
{
  __shared__ unsigned short R0[256*72];   // proj bf16 [m][d]; q-blocks overlay qS [64][264]
  __shared__ unsigned short xbS[64*72];   // NRM-scaled bf16 x [row][d]
  __shared__ float diagS[64];
  __shared__ float rmS[4*64];
  const int t=threadIdx.x, bb=blockIdx.x;
  const bool isq = bb >= NCH_;
  const int blk = bb & (NCH_-1);
  const float* x = isq ? qg : kg;
  const int row0 = blk*64;
  const int lane=t&63, m16=lane&15, q4=lane>>4, w=t>>6;
  const int f0 = w*64;

#pragma unroll
  for (int i=0;i<8;++i){ int flat=i*2048+t*8; int f=flat>>6, d2=flat&63;
    float4 p0 = *(const float4*)(projg+flat);
    float4 p1 = *(const float4*)(projg+flat+4);
    *(uint4*)&R0[f*72+d2] = make_uint4(pk2f(p0.x,p0.y),pk2f(p0.z,p0.w),
                                       pk2f(p1.x,p1.y),pk2f(p1.z,p1.w)); }
  {  // x staging (bf16, scaled) + diag reduction over each row's 16 staging lanes
    const float* xg = x + (size_t)row0*64;
#pragma unroll
    for (int i=0;i<4;++i){
      int flat=i*1024+t*4; int r=flat>>6, d2=flat&63;
      float4 f = *(const float4*)(xg+flat);
      float ss = sumsq4(f);
      ss += __shfl_xor(ss,1); ss += __shfl_xor(ss,2);
      ss += __shfl_xor(ss,4); ss += __shfl_xor(ss,8);
      if ((t&15)==0) diagS[r] = 0.0625f*ss;   // 0.5*nrm^2*sum(x^2)
      *(uint2*)&xbS[r*72+d2] = make_uint2(pk2f(NRM_*f.x,NRM_*f.y), pk2f(NRM_*f.z,NRM_*f.w));
    }
  }
  __syncthreads();

  bf16x8 b[4][2]; float diag4[4];
#pragma unroll
  for (int rt=0;rt<4;++rt){
    b[rt][0] = *(const bf16x8*)&xbS[(rt*16+m16)*72 + q4*8];
    b[rt][1] = *(const bf16x8*)&xbS[(rt*16+m16)*72 + 32 + q4*8];
    diag4[rt] = diagS[rt*16+m16];
  }

  f32x4 acc[4][4];
#pragma unroll
  for (int rt=0;rt<4;++rt)
#pragma unroll
    for (int mt=0;mt<4;++mt) acc[rt][mt] = (f32x4){0.f,0.f,0.f,0.f};
#pragma unroll
  for (int kk=0;kk<2;++kk)
#pragma unroll
    for (int mt=0;mt<4;++mt){
      bf16x8 a = *(const bf16x8*)&R0[(f0+mt*16+m16)*72 + kk*32 + q4*8];
#pragma unroll
      for (int rt=0;rt<4;++rt)
        acc[rt][mt] = MFMA(a, b[rt][kk], acc[rt][mt]);
    }

  if (!isq) {
    float mx = acc[0][0][0];
#pragma unroll
    for (int rt=0;rt<4;++rt)
#pragma unroll
      for (int mt=0;mt<4;++mt)
#pragma unroll
        for (int j=0;j<4;++j) mx = fmaxf(mx, acc[rt][mt][j]);
#pragma unroll
    for (int off=1; off<64; off<<=1) mx = fmaxf(mx, __shfl_xor(mx, off));
    if (lane == 0) rmS[w*64] = mx;
    __syncthreads();
    if (t == 0)
      blockmax[blk] = fmaxf(fmaxf(rmS[0],rmS[64]),fmaxf(rmS[128],rmS[192]));
  } else {
    unsigned short* qS = R0;
#pragma unroll
    for (int rt=0;rt<4;++rt){
      float p = acc[rt][0][0];
#pragma unroll
      for (int mt=0;mt<4;++mt)
#pragma unroll
        for (int j=0;j<4;++j) p = fmaxf(p, acc[rt][mt][j]);
      p = fmaxf(p, __shfl_xor(p,16)); p = fmaxf(p, __shfl_xor(p,32));
      if (q4 == 0) rmS[w*64 + rt*16+m16] = p;
    }
    __syncthreads();   // rmS ready; proj reads done -> overlay safe
#pragma unroll
    for (int rt=0;rt<4;++rt){
      int rr = rt*16+m16;
      float rm = fmaxf(fmaxf(rmS[rr],rmS[64+rr]),fmaxf(rmS[128+rr],rmS[192+rr]));
      float e = diag4[rt] + rm;
#pragma unroll
      for (int mt=0;mt<4;++mt){
        float v0 = RATIO_*(__expf(acc[rt][mt][0]-e)+1e-4f);
        float v1 = RATIO_*(__expf(acc[rt][mt][1]-e)+1e-4f);
        float v2 = RATIO_*(__expf(acc[rt][mt][2]-e)+1e-4f);
        float v3 = RATIO_*(__expf(acc[rt][mt][3]-e)+1e-4f);
        *(uint2*)&qS[rr*264 + f0 + mt*16 + q4*4] = make_uint2(pk2f(v0,v1), pk2f(v2,v3));
      }
    }
    __syncthreads();
    // A-frag-packed store
#pragma unroll
    for (int i=0;i<8;++i){
      int bidx = i*256 + t;
      int wp = bidx>>9, m16p = (bidx>>2)&15, kkp = (bidx>>6)&7, q4p = bidx&3;
      *(uint4*)(qpP + (size_t)blk*16384 + bidx*8) =
          *(const uint4*)&qS[(wp*16+m16p)*264 + kkp*32 + q4p*8];
    }
  }
}

// K2: k GEMM + exp -> kpP (A-frag-packed) + chunk-sum GEMM -> kvxP (B-frag-packed).
// x staged as scaled bf16 into the kpT buffer (overlay; xbS dead before kpT writes).
__global__ __launch_bounds__(256, 2) void kexp_kernel(
    const float* __restrict__ kg, const float* __restrict__ vg,
    const float* __restrict__ projg, const float* __restrict__ blockmax,
    unsigned short* __restrict__ kpP, unsigned short* __restrict__ kvxP)
{
  __shared__ unsigned short A_[256*72];    // proj -> overlay kpS [64][264]
  __shared__ unsigned short kpTb[128*72];  // staging: xbS [64][72]; later kpT [128][72]
  __shared__ unsigned short C_[80*72];     // vext [c][s]
  __shared__ float diagS[64];
  __shared__ float kmS;
  const int t=threadIdx.x, ch=blockIdx.x;
  const int row0 = ch*64;
  const int lane=t&63, m16=lane&15, q4=lane>>4, w=t>>6;
  const int f0 = w*64;
  unsigned short* kpS = A_;
  unsigned short* xbS = kpTb;
  unsigned short* kpT = kpTb;

#pragma unroll
  for (int i=0;i<8;++i){ int flat=i*2048+t*8; int f=flat>>6, d2=flat&63;
    float4 p0 = *(const float4*)(projg+flat);
    float4 p1 = *(const float4*)(projg+flat+4);
    *(uint4*)&A_[f*72+d2] = make_uint4(pk2f(p0.x,p0.y),pk2f(p0.z,p0.w),
                                       pk2f(p1.x,p1.y),pk2f(p1.z,p1.w)); }
  {  // x staging (bf16, scaled) + diag
    const float* xg = kg + (size_t)row0*64;
#pragma unroll
    for (int i=0;i<4;++i){
      int flat=i*1024+t*4; int r=flat>>6, d2=flat&63;
      float4 f = *(const float4*)(xg+flat);
      float ss = sumsq4(f);
      ss += __shfl_xor(ss,1); ss += __shfl_xor(ss,2);
      ss += __shfl_xor(ss,4); ss += __shfl_xor(ss,8);
      if ((t&15)==0) diagS[r] = 0.0625f*ss;
      *(uint2*)&xbS[r*72+d2] = make_uint2(pk2f(NRM_*f.x,NRM_*f.y), pk2f(NRM_*f.z,NRM_*f.w));
    }
  }
  {  // vext: coalesced v loads, strided u16 LDS writes
    int c = t&63, sq_ = t>>6;
#pragma unroll
    for (int i=0;i<16;++i)
      C_[c*72 + sq_*16 + i] = f2b(vg[((size_t)row0 + sq_*16 + i)*64 + c]);
    int cc = 64 + (t>>4), s4 = (t&15)*4;
    unsigned short hv = (cc==64) ? (unsigned short)0x3F80 : (unsigned short)0;
    unsigned pv = (unsigned)hv | ((unsigned)hv<<16);
    *(uint2*)&C_[cc*72 + s4] = make_uint2(pv, pv);
  }
  if (t < 32) {
    float bm = blockmax[(ch>>5)*32 + t];
#pragma unroll
    for (int off=16; off>=1; off>>=1) bm = fmaxf(bm, __shfl_xor(bm, off));
    if (t == 0) kmS = bm;
  }
  __syncthreads();

  bf16x8 b[4][2]; float diag4[4];
#pragma unroll
  for (int rt=0;rt<4;++rt){
    b[rt][0] = *(const bf16x8*)&xbS[(rt*16+m16)*72 + q4*8];
    b[rt][1] = *(const bf16x8*)&xbS[(rt*16+m16)*72 + 32 + q4*8];
    diag4[rt] = diagS[rt*16+m16];
  }
  const float kmx = kmS;

  f32x4 acc[4][4];
#pragma unroll
  for (int rt=0;rt<4;++rt)
#pragma unroll
    for (int mt=0;mt<4;++mt) acc[rt][mt] = (f32x4){0.f,0.f,0.f,0.f};
#pragma unroll
  for (int kk=0;kk<2;++kk)
#pragma unroll
    for (int mt=0;mt<4;++mt){
      bf16x8 a = *(const bf16x8*)&A_[(f0+mt*16+m16)*72 + kk*32 + q4*8];
#pragma unroll
      for (int rt=0;rt<4;++rt)
        acc[rt][mt] = MFMA(a, b[rt][kk], acc[rt][mt]);
    }
  __syncthreads();   // proj/x LDS reads done -> overlays (kpS, kpT) safe

  unsigned kpx[4][4][2];
#pragma unroll
  for (int rt=0;rt<4;++rt){
    float e = diag4[rt] + kmx;
    int rr = rt*16+m16;
#pragma unroll
    for (int mt=0;mt<4;++mt){
      float v0 = RATIO_*(__expf(acc[rt][mt][0]-e)+1e-4f);
      float v1 = RATIO_*(__expf(acc[rt][mt][1]-e)+1e-4f);
      float v2 = RATIO_*(__expf(acc[rt][mt][2]-e)+1e-4f);
      float v3 = RATIO_*(__expf(acc[rt][mt][3]-e)+1e-4f);
      kpx[rt][mt][0] = pk2f(v0,v1); kpx[rt][mt][1] = pk2f(v2,v3);
      *(uint2*)&kpS[rr*264 + f0 + mt*16 + q4*4] = make_uint2(kpx[rt][mt][0], kpx[rt][mt][1]);
    }
  }
  if ((w>>1) == 0) {   // kpT half 0 (features 0..127)
#pragma unroll
    for (int rt=0;rt<4;++rt)
#pragma unroll
      for (int mt=0;mt<4;++mt)
#pragma unroll
        for (int jp=0;jp<2;++jp){
          int frl = (w&1)*64 + mt*16 + q4*4 + jp*2;
          unsigned uv = kpx[rt][mt][jp];
          kpT[frl*72 + rt*16+m16]     = (unsigned short)uv;
          kpT[(frl+1)*72 + rt*16+m16] = (unsigned short)(uv>>16);
        }
  }
  __syncthreads();
  // kpP store, A-frag-packed (identical structure to qpP)
#pragma unroll
  for (int i=0;i<8;++i){
    int bidx = i*256 + t;
    int wp = bidx>>9, m16p = (bidx>>2)&15, kkp = (bidx>>6)&7, q4p = bidx&3;
    *(uint4*)(kpP + (size_t)ch*16384 + bidx*8) =
        *(const uint4*)&kpS[(wp*16+m16p)*264 + kkp*32 + q4p*8];
  }
  // chunk-sum GEMM halves -> kvxP B-frag-packed
#pragma unroll
  for (int h=0; h<2; ++h) {
    if (h == 1) {
      __syncthreads();
      if ((w>>1) == 1) {
#pragma unroll
        for (int rt=0;rt<4;++rt)
#pragma unroll
          for (int mt=0;mt<4;++mt)
#pragma unroll
            for (int jp=0;jp<2;++jp){
              int frl = (w&1)*64 + mt*16 + q4*4 + jp*2;
              unsigned uv = kpx[rt][mt][jp];
              kpT[frl*72 + rt*16+m16]     = (unsigned short)uv;
              kpT[(frl+1)*72 + rt*16+m16] = (unsigned short)(uv>>16);
            }
      }
      __syncthreads();
    }
    f32x4 c2a[5][2];
#pragma unroll
    for (int ct=0;ct<5;++ct)
#pragma unroll
      for (int p=0;p<2;++p) c2a[ct][p] = (f32x4){0.f,0.f,0.f,0.f};
#pragma unroll
    for (int kk=0;kk<2;++kk){
      bf16x8 av[5];
#pragma unroll
      for (int ct=0;ct<5;++ct)
        av[ct] = *(const bf16x8*)&C_[(ct*16+m16)*72 + kk*32 + q4*8];
#pragma unroll
      for (int p=0;p<2;++p){
        int mtl = w*2 + p;
        bf16x8 bv = *(const bf16x8*)&kpT[(mtl*16+m16)*72 + kk*32 + q4*8];
#pragma unroll
        for (int ct=0;ct<5;++ct)
          c2a[ct][p] = MFMA(av[ct], bv, c2a[ct][p]);
      }
    }
    // B-frag-packed: fb = (m>>5)*512 + ((m>>3)&3)*8 + (m&7), + c16*32
#pragma unroll
    for (int ct=0;ct<5;++ct)
#pragma unroll
      for (int p=0;p<2;++p){
        int mtg = h*8 + w*2 + p;
        int mrow = mtg*16 + m16;
        int fb = (mrow>>5)*512 + ((mrow>>3)&3)*8 + (mrow&7);
        unsigned short* dst = kvxP + (size_t)(ch*5+ct)*4096 + fb + (q4*4)*32;
#pragma unroll
        for (int j=0;j<4;++j)
          dst[j*32] = f2b(c2a[ct][p][j]);
      }
    if (h == 0) __syncthreads();
  }
}

// K3: exclusive prefix over 32 chunks (coalesced packed->packed, register carry).
__global__ __launch_bounds__(256, 4) void scan_kernel(
    const unsigned short* __restrict__ kvxP, unsigned short* __restrict__ sxP)
{
  const int t = threadIdx.x, bid = blockIdx.x;   // 0..319
  const int qtr = bid & 3, ct = (bid>>2)%5, bh = bid/20;
  const int fbase = qtr*1024 + t*4;
  const bool isEps = (ct==4) && (((fbase>>5)&15) == 1);
  float carry0=0.f, carry1=0.f, carry2=0.f, carry3=0.f;
  const size_t stride = (size_t)5*4096;
  size_t base = ((size_t)(bh*32)*5 + ct)*4096 + fbase;
#pragma unroll 4
  for (int chl=0; chl<32; ++chl){
    unsigned s0, s1;
    if (isEps) { unsigned ee = pk2f(1e-6f,1e-6f); s0 = ee; s1 = ee; }
    else { s0 = pk2f(carry0,carry1); s1 = pk2f(carry2,carry3); }
    *(uint2*)(sxP + base) = make_uint2(s0, s1);
    uint2 raw = *(const uint2*)(kvxP + base);
    carry0 += b2f((unsigned short)(raw.x));
    carry1 += b2f((unsigned short)(raw.x>>16));
    carry2 += b2f((unsigned short)(raw.y));
    carry3 += b2f((unsigned short)(raw.y>>16));
    base += stride;
  }
}

// K4: all fragments direct from global, contiguous 1KB wave loads.
// LDS only vext + P + oT overlay (~21KB) -> 4 blocks/CU.
__global__ __launch_bounds__(256, 4) void out_kernel(
    const unsigned short* __restrict__ qpP, const unsigned short* __restrict__ kpP,
    const unsigned short* __restrict__ sxP, const float* __restrict__ vg,
    float* __restrict__ out_g)
{
  __shared__ __align__(16) unsigned char ldsb[80*72*2 + 64*72*2];  // 20.7 KB
  unsigned short* vx = (unsigned short*)ldsb;              // [80][72]
  unsigned short* P  = (unsigned short*)(ldsb + 80*72*2);  // [64][72]
  float* oT = (float*)ldsb;                                // overlay: [64][68] f32
  const int t=threadIdx.x, ch=blockIdx.x;
  const int row0 = ch*64;
  const int lane=t&63, m16=lane&15, q4=lane>>4, w=t>>6;
  const int r0 = w*16;

  {  // stage vext
    int c = t&63, sq_ = t>>6;
#pragma unroll
    for (int i=0;i<16;++i)
      vx[c*72 + sq_*16 + i] = f2b(vg[((size_t)row0 + sq_*16 + i)*64 + c]);
    int cc = 64 + (t>>4), s4 = (t&15)*4;
    unsigned short hv = (cc==64) ? (unsigned short)0x3F80 : (unsigned short)0;
    unsigned pv = (unsigned)hv | ((unsigned)hv<<16);
    *(uint2*)&vx[cc*72 + s4] = make_uint2(pv, pv);
  }

  f32x4 accA[4], accO[5];
#pragma unroll
  for (int i=0;i<4;++i) accA[i] = (f32x4){0.f,0.f,0.f,0.f};
#pragma unroll
  for (int i=0;i<5;++i) accO[i] = (f32x4){0.f,0.f,0.f,0.f};
  const unsigned short* qpw = qpP + (size_t)ch*16384 + (size_t)w*4096 + m16*32 + q4*8;
  const unsigned short* kpb = kpP + (size_t)ch*16384 + m16*32 + q4*8;
  const unsigned short* sxb = sxP + (size_t)ch*5*4096 + m16*32 + q4*8;
#pragma unroll
  for (int kk=0;kk<8;++kk){
    bf16x8 a = *(const bf16x8*)(qpw + kk*512);
#pragma unroll
    for (int st=0;st<4;++st)
      accA[st] = MFMA(a, *(const bf16x8*)(kpb + (size_t)st*4096 + kk*512), accA[st]);
#pragma unroll
    for (int ct=0;ct<5;++ct)
      accO[ct] = MFMA(a, *(const bf16x8*)(sxb + (size_t)ct*4096 + kk*512), accO[ct]);
  }
  __syncthreads();   // vext staged (P region untouched until now)

  // causal mask -> P (wave-local rows)
#pragma unroll
  for (int st=0;st<4;++st)
#pragma unroll
    for (int j=0;j<4;++j){
      int rr = r0 + q4*4 + j;
      int cc = st*16 + m16;
      P[rr*72 + cc] = f2b((cc<=rr) ? accA[st][j] : 0.f);
    }
#pragma unroll
  for (int k2=0;k2<2;++k2){
    bf16x8 aP = *(const bf16x8*)&P[(r0+m16)*72 + k2*32 + q4*8];
#pragma unroll
    for (int ct=0;ct<5;++ct){
      bf16x8 bfr = *(const bf16x8*)&vx[(ct*16+m16)*72 + k2*32 + q4*8];
      accO[ct] = MFMA(aP, bfr, accO[ct]);
    }
  }
  __syncthreads();   // P/vx reads done -> oT overlay safe
#pragma unroll
  for (int j=0;j<4;++j){
    float d64 = __shfl(accO[4][j], (lane & 48));
    float d65 = __shfl(accO[4][j], (lane & 48) | 1);
    float dinv = 1.f/(d64+d65);
    int rr = r0 + q4*4 + j;
#pragma unroll
    for (int ct=0;ct<4;++ct)
      oT[rr*68 + ct*16 + m16] = accO[ct][j]*dinv;
  }
  __syncthreads();
#pragma unroll
  for (int i=0;i<4;++i){ int flat=i*1024+t*4; int r=flat>>6, c2=flat&63;
    *(float4*)(out_g + (size_t)row0*64 + flat) = *(const float4*)&oT[r*68+c2]; }
}

extern "C" void kernel_launch(void* const* d_in, const int* in_sizes, int n_in,
                              void* d_out, int out_size, void* d_ws, size_t ws_size,
                              hipStream_t stream)
{
  (void)in_sizes; (void)n_in; (void)out_size; (void)ws_size;
  const float* q    = (const float*)d_in[0];
  const float* k    = (const float*)d_in[1];
  const float* v    = (const float*)d_in[2];
  const float* proj = (const float*)d_in[3];
  float* out = (float*)d_out;

  char* p8 = (char*)d_ws;
  unsigned short* qpP  = (unsigned short*)p8; p8 += (size_t)NCH_*16384*2;   // 16.78 MB
  unsigned short* kpP  = (unsigned short*)p8; p8 += (size_t)NCH_*16384*2;   // 16.78 MB
  unsigned short* kvxP = (unsigned short*)p8; p8 += (size_t)NCH_*5*4096*2;  // 20.97 MB
  unsigned short* sxP  = (unsigned short*)p8; p8 += (size_t)NCH_*5*4096*2;  // 20.97 MB
  float* blockmax = (float*)p8;

  feat_all   <<<dim3(2*NCH_), dim3(256), 0, stream>>>(q, k, proj, qpP, blockmax);
  kexp_kernel<<<dim3(NCH_),   dim3(256), 0, stream>>>(k, v, proj, blockmax, kpP, kvxP);
  scan_kernel<<<dim3(320),    dim3(256), 0, stream>>>(kvxP, sxP);
  out_kernel <<<dim3(NCH_),   dim3(256), 0, stream>>>(qpP, kpP, sxP, v, out);
}

// Round 13
// 115.203 us; speedup vs baseline: 2.8525x; 1.1329x over previous
//
#include <hip/hip_runtime.h>
#include <hip/hip_bf16.h>
#include <cstddef>

typedef __attribute__((ext_vector_type(8))) short bf16x8;
typedef __attribute__((ext_vector_type(4))) float f32x4;

#define NCH_ 512
#define NRM_ 0.35355339059327373f  // 64^-0.25
#define RATIO_ 0.0625f             // 256^-0.5
#define EPSC_ 6.25e-6f             // RATIO_*1e-4 (k' eps, applied analytically)
#define MFMA(a,b,c) __builtin_amdgcn_mfma_f32_16x16x32_bf16((a),(b),(c),0,0,0)

__device__ __forceinline__ unsigned short f2b(float f) {
  unsigned u = __float_as_uint(f);
  u += 0x7FFFu + ((u >> 16) & 1u);
  return (unsigned short)(u >> 16);
}
__device__ __forceinline__ float b2f(unsigned short h) {
  return __uint_as_float(((unsigned)h) << 16);
}
__device__ __forceinline__ unsigned pk2f(float a, float b) {
  union { __hip_bfloat162 h; unsigned u; } cv;
  cv.h = __float22bfloat162_rn(make_float2(a, b));
  return cv.u;
}
__device__ __forceinline__ float sumsq4(float4 a){ return a.x*a.x+a.y*a.y+a.z*a.z+a.w*a.w; }

// K1: k chunk pass. GEMM once; Gr = RATIO*exp(xd-diag-cmax) with chunk-local cmax.
// Writes: kpL (A-frag-packed Gr), kvxP (B-frag-packed C2L = Vext^T@Gr),
//         blockmax[ch]=cmax, vsumG[ch][c]=colsum(Vext).
__global__ __launch_bounds__(256, 2) void kfeat_kernel(
    const float* __restrict__ kg, const float* __restrict__ vg,
    const float* __restrict__ projg,
    unsigned short* __restrict__ kpL, unsigned short* __restrict__ kvxP,
    float* __restrict__ blockmax, float* __restrict__ vsumG)
{
  __shared__ unsigned short R0[256*72];   // proj bf16 -> overlay kpS [64][264]
  __shared__ unsigned short XB[128*72];   // xbS [64][72] -> overlay kpT [128][72]
  __shared__ unsigned short C_[80*72];    // vext [c][s]
  __shared__ float diagS[64];
  __shared__ float rmS[4];
  const int t=threadIdx.x, ch=blockIdx.x;
  const int row0 = ch*64;
  const int lane=t&63, m16=lane&15, q4=lane>>4, w=t>>6;
  const int f0 = w*64;
  unsigned short* kpS = R0;
  unsigned short* xbS = XB;
  unsigned short* kpT = XB;

#pragma unroll
  for (int i=0;i<8;++i){ int flat=i*2048+t*8; int f=flat>>6, d2=flat&63;
    float4 p0 = *(const float4*)(projg+flat);
    float4 p1 = *(const float4*)(projg+flat+4);
    *(uint4*)&R0[f*72+d2] = make_uint4(pk2f(p0.x,p0.y),pk2f(p0.z,p0.w),
                                       pk2f(p1.x,p1.y),pk2f(p1.z,p1.w)); }
  {  // k staging (bf16, scaled) + diag
    const float* xg = kg + (size_t)row0*64;
#pragma unroll
    for (int i=0;i<4;++i){
      int flat=i*1024+t*4; int r=flat>>6, d2=flat&63;
      float4 f = *(const float4*)(xg+flat);
      float ss = sumsq4(f);
      ss += __shfl_xor(ss,1); ss += __shfl_xor(ss,2);
      ss += __shfl_xor(ss,4); ss += __shfl_xor(ss,8);
      if ((t&15)==0) diagS[r] = 0.0625f*ss;
      *(uint2*)&xbS[r*72+d2] = make_uint2(pk2f(NRM_*f.x,NRM_*f.y), pk2f(NRM_*f.z,NRM_*f.w));
    }
  }
  {  // vext staging
    int c = t&63, sq_ = t>>6;
#pragma unroll
    for (int i=0;i<16;++i)
      C_[c*72 + sq_*16 + i] = f2b(vg[((size_t)row0 + sq_*16 + i)*64 + c]);
    int cc = 64 + (t>>4), s4 = (t&15)*4;
    unsigned short hv = (cc==64) ? (unsigned short)0x3F80 : (unsigned short)0;
    unsigned pv = (unsigned)hv | ((unsigned)hv<<16);
    *(uint2*)&C_[cc*72 + s4] = make_uint2(pv, pv);
  }
  __syncthreads();

  // vsum (colsum of Vext) — 80 threads
  if (t < 80) {
    float s = 0.f;
#pragma unroll 16
    for (int i=0;i<64;++i) s += b2f(C_[t*72+i]);
    vsumG[(size_t)ch*80 + t] = s;
  }

  bf16x8 b[4][2]; float diag4[4];
#pragma unroll
  for (int rt=0;rt<4;++rt){
    b[rt][0] = *(const bf16x8*)&xbS[(rt*16+m16)*72 + q4*8];
    b[rt][1] = *(const bf16x8*)&xbS[(rt*16+m16)*72 + 32 + q4*8];
    diag4[rt] = diagS[rt*16+m16];
  }
  f32x4 acc[4][4];
#pragma unroll
  for (int rt=0;rt<4;++rt)
#pragma unroll
    for (int mt=0;mt<4;++mt) acc[rt][mt] = (f32x4){0.f,0.f,0.f,0.f};
#pragma unroll
  for (int kk=0;kk<2;++kk)
#pragma unroll
    for (int mt=0;mt<4;++mt){
      bf16x8 a = *(const bf16x8*)&R0[(f0+mt*16+m16)*72 + kk*32 + q4*8];
#pragma unroll
      for (int rt=0;rt<4;++rt)
        acc[rt][mt] = MFMA(a, b[rt][kk], acc[rt][mt]);
    }
  // chunk max -> cmax (all threads), publish blockmax
  {
    float mx = acc[0][0][0];
#pragma unroll
    for (int rt=0;rt<4;++rt)
#pragma unroll
      for (int mt=0;mt<4;++mt)
#pragma unroll
        for (int j=0;j<4;++j) mx = fmaxf(mx, acc[rt][mt][j]);
#pragma unroll
    for (int off=1; off<64; off<<=1) mx = fmaxf(mx, __shfl_xor(mx, off));
    if (lane == 0) rmS[w] = mx;
  }
  __syncthreads();   // rmS ready; proj/xbS reads done -> overlays safe
  const float cmax = fmaxf(fmaxf(rmS[0],rmS[1]),fmaxf(rmS[2],rmS[3]));
  if (t == 0) blockmax[ch] = cmax;

  unsigned kpx[4][4][2];
#pragma unroll
  for (int rt=0;rt<4;++rt){
    float e = diag4[rt] + cmax;
    int rr = rt*16+m16;
#pragma unroll
    for (int mt=0;mt<4;++mt){
      float v0 = RATIO_*__expf(acc[rt][mt][0]-e);   // Gr (no eps — analytic)
      float v1 = RATIO_*__expf(acc[rt][mt][1]-e);
      float v2 = RATIO_*__expf(acc[rt][mt][2]-e);
      float v3 = RATIO_*__expf(acc[rt][mt][3]-e);
      kpx[rt][mt][0] = pk2f(v0,v1); kpx[rt][mt][1] = pk2f(v2,v3);
      *(uint2*)&kpS[rr*264 + f0 + mt*16 + q4*4] = make_uint2(kpx[rt][mt][0], kpx[rt][mt][1]);
    }
  }
  if ((w>>1) == 0) {   // kpT half 0 (features 0..127)
#pragma unroll
    for (int rt=0;rt<4;++rt)
#pragma unroll
      for (int mt=0;mt<4;++mt)
#pragma unroll
        for (int jp=0;jp<2;++jp){
          int frl = (w&1)*64 + mt*16 + q4*4 + jp*2;
          unsigned uv = kpx[rt][mt][jp];
          kpT[frl*72 + rt*16+m16]     = (unsigned short)uv;
          kpT[(frl+1)*72 + rt*16+m16] = (unsigned short)(uv>>16);
        }
  }
  __syncthreads();
  // kpL packed store (A-frag layout)
#pragma unroll
  for (int i=0;i<8;++i){
    int bidx = i*256 + t;
    int wp = bidx>>9, m16p = (bidx>>2)&15, kkp = (bidx>>6)&7, q4p = bidx&3;
    *(uint4*)(kpL + (size_t)ch*16384 + bidx*8) =
        *(const uint4*)&kpS[(wp*16+m16p)*264 + kkp*32 + q4p*8];
  }
  // chunk-sum GEMM halves -> kvxP (B-frag-packed), values = C2L (uncorrected)
#pragma unroll
  for (int h=0; h<2; ++h) {
    if (h == 1) {
      __syncthreads();
      if ((w>>1) == 1) {
#pragma unroll
        for (int rt=0;rt<4;++rt)
#pragma unroll
          for (int mt=0;mt<4;++mt)
#pragma unroll
            for (int jp=0;jp<2;++jp){
              int frl = (w&1)*64 + mt*16 + q4*4 + jp*2;
              unsigned uv = kpx[rt][mt][jp];
              kpT[frl*72 + rt*16+m16]     = (unsigned short)uv;
              kpT[(frl+1)*72 + rt*16+m16] = (unsigned short)(uv>>16);
            }
      }
      __syncthreads();
    }
    f32x4 c2a[5][2];
#pragma unroll
    for (int ct=0;ct<5;++ct)
#pragma unroll
      for (int p=0;p<2;++p) c2a[ct][p] = (f32x4){0.f,0.f,0.f,0.f};
#pragma unroll
    for (int kk=0;kk<2;++kk){
      bf16x8 av[5];
#pragma unroll
      for (int ct=0;ct<5;++ct)
        av[ct] = *(const bf16x8*)&C_[(ct*16+m16)*72 + kk*32 + q4*8];
#pragma unroll
      for (int p=0;p<2;++p){
        int mtl = w*2 + p;
        bf16x8 bv = *(const bf16x8*)&kpT[(mtl*16+m16)*72 + kk*32 + q4*8];
#pragma unroll
        for (int ct=0;ct<5;++ct)
          c2a[ct][p] = MFMA(av[ct], bv, c2a[ct][p]);
      }
    }
#pragma unroll
    for (int ct=0;ct<5;++ct)
#pragma unroll
      for (int p=0;p<2;++p){
        int mtg = h*8 + w*2 + p;
        int mrow = mtg*16 + m16;
        int fb = (mrow>>5)*512 + ((mrow>>3)&3)*8 + (mrow&7);
        unsigned short* dst = kvxP + (size_t)(ch*5+ct)*4096 + fb + (q4*4)*32;
#pragma unroll
        for (int j=0;j<4;++j)
          dst[j*32] = f2b(c2a[ct][p][j]);
      }
    if (h == 0) __syncthreads();
  }
}

// K2: exclusive prefix over 32 chunks with correction: contribution = s_chl*C2L + EPSC*vsum.
__global__ __launch_bounds__(256, 4) void scan_kernel(
    const unsigned short* __restrict__ kvxP, unsigned short* __restrict__ sxP,
    const float* __restrict__ blockmax, const float* __restrict__ vsumG)
{
  __shared__ float sS[32];
  __shared__ float vsS[32][16];
  const int t = threadIdx.x, bid = blockIdx.x;   // 0..319
  const int qtr = bid & 3, ct = (bid>>2)%5, bh = bid/20;
  if (t < 32) {
    float bm = blockmax[bh*32 + t];
    float km = bm;
#pragma unroll
    for (int off=16; off>=1; off>>=1) km = fmaxf(km, __shfl_xor(km, off));
    sS[t] = __expf(bm - km);
  }
  for (int i=t; i<512; i+=256){
    int chl = i>>4, c16 = i&15;
    vsS[chl][c16] = vsumG[(size_t)(bh*32+chl)*80 + ct*16 + c16];
  }
  __syncthreads();
  const int fbase = qtr*1024 + t*4;
  const int c16t = (t>>3)&15;
  const bool isEps = (ct==4) && (c16t == 1);
  float carry0=0.f, carry1=0.f, carry2=0.f, carry3=0.f;
  const size_t stride = (size_t)5*4096;
  size_t base = ((size_t)(bh*32)*5 + ct)*4096 + fbase;
#pragma unroll 4
  for (int chl=0; chl<32; ++chl){
    unsigned s0, s1;
    if (isEps) { unsigned ee = pk2f(1e-6f,1e-6f); s0 = ee; s1 = ee; }
    else { s0 = pk2f(carry0,carry1); s1 = pk2f(carry2,carry3); }
    *(uint2*)(sxP + base) = make_uint2(s0, s1);
    uint2 raw = *(const uint2*)(kvxP + base);
    float sch = sS[chl];
    float evs = EPSC_ * vsS[chl][c16t];
    carry0 += sch*b2f((unsigned short)(raw.x))     + evs;
    carry1 += sch*b2f((unsigned short)(raw.x>>16)) + evs;
    carry2 += sch*b2f((unsigned short)(raw.y))     + evs;
    carry3 += sch*b2f((unsigned short)(raw.y>>16)) + evs;
    base += stride;
  }
}

// K3: q-features (staged proj/q, GEMM, rowmax, exp -> aq regs) fused with output:
// AL = Q'@Gr^T ; P = s_ch*AL + EPSC*q1 (masked) ; O = Q'@Sx + P@Vext ; den cols 64/65.
__global__ __launch_bounds__(256, 2) void out_kernel(
    const float* __restrict__ qg, const float* __restrict__ projg,
    const unsigned short* __restrict__ kpL, const unsigned short* __restrict__ sxP,
    const float* __restrict__ vg, const float* __restrict__ blockmax,
    float* __restrict__ out_g)
{
  __shared__ unsigned short R0[256*72];   // proj -> qS [64][264] -> oT f32[64][68]
  __shared__ unsigned short XB[64*72];    // xbS (q bf16) -> P [64][72]
  __shared__ unsigned short C_[80*72];    // vext
  __shared__ float diagS[64];
  __shared__ float rmS[4*64];
  __shared__ float schS;
  const int t=threadIdx.x, ch=blockIdx.x;
  const int row0 = ch*64;
  const int lane=t&63, m16=lane&15, q4=lane>>4, w=t>>6;
  const int f0 = w*64, r0 = w*16;
  unsigned short* xbS = XB;
  unsigned short* P   = XB;

#pragma unroll
  for (int i=0;i<8;++i){ int flat=i*2048+t*8; int f=flat>>6, d2=flat&63;
    float4 p0 = *(const float4*)(projg+flat);
    float4 p1 = *(const float4*)(projg+flat+4);
    *(uint4*)&R0[f*72+d2] = make_uint4(pk2f(p0.x,p0.y),pk2f(p0.z,p0.w),
                                       pk2f(p1.x,p1.y),pk2f(p1.z,p1.w)); }
  {  // q staging (bf16, scaled) + diag
    const float* xg = qg + (size_t)row0*64;
#pragma unroll
    for (int i=0;i<4;++i){
      int flat=i*1024+t*4; int r=flat>>6, d2=flat&63;
      float4 f = *(const float4*)(xg+flat);
      float ss = sumsq4(f);
      ss += __shfl_xor(ss,1); ss += __shfl_xor(ss,2);
      ss += __shfl_xor(ss,4); ss += __shfl_xor(ss,8);
      if ((t&15)==0) diagS[r] = 0.0625f*ss;
      *(uint2*)&xbS[r*72+d2] = make_uint2(pk2f(NRM_*f.x,NRM_*f.y), pk2f(NRM_*f.z,NRM_*f.w));
    }
  }
  {  // vext staging
    int c = t&63, sq_ = t>>6;
#pragma unroll
    for (int i=0;i<16;++i)
      C_[c*72 + sq_*16 + i] = f2b(vg[((size_t)row0 + sq_*16 + i)*64 + c]);
    int cc = 64 + (t>>4), s4 = (t&15)*4;
    unsigned short hv = (cc==64) ? (unsigned short)0x3F80 : (unsigned short)0;
    unsigned pv = (unsigned)hv | ((unsigned)hv<<16);
    *(uint2*)&C_[cc*72 + s4] = make_uint2(pv, pv);
  }
  if (t < 32) {   // s_ch = exp(cmax_ch - kmax_bh)
    float bm = blockmax[(ch>>5)*32 + t];
    float km = bm;
#pragma unroll
    for (int off=16; off>=1; off>>=1) km = fmaxf(km, __shfl_xor(km, off));
    if (t == (ch & 31)) schS = __expf(bm - km);
  }
  __syncthreads();

  // q-GEMM
  bf16x8 b[4][2]; float diag4[4];
#pragma unroll
  for (int rt=0;rt<4;++rt){
    b[rt][0] = *(const bf16x8*)&xbS[(rt*16+m16)*72 + q4*8];
    b[rt][1] = *(const bf16x8*)&xbS[(rt*16+m16)*72 + 32 + q4*8];
    diag4[rt] = diagS[rt*16+m16];
  }
  f32x4 acc[4][4];
#pragma unroll
  for (int rt=0;rt<4;++rt)
#pragma unroll
    for (int mt=0;mt<4;++mt) acc[rt][mt] = (f32x4){0.f,0.f,0.f,0.f};
#pragma unroll
  for (int kk=0;kk<2;++kk)
#pragma unroll
    for (int mt=0;mt<4;++mt){
      bf16x8 a = *(const bf16x8*)&R0[(f0+mt*16+m16)*72 + kk*32 + q4*8];
#pragma unroll
      for (int rt=0;rt<4;++rt)
        acc[rt][mt] = MFMA(a, b[rt][kk], acc[rt][mt]);
    }
  // per-row max (cross-wave)
#pragma unroll
  for (int rt=0;rt<4;++rt){
    float p = acc[rt][0][0];
#pragma unroll
    for (int mt=0;mt<4;++mt)
#pragma unroll
      for (int j=0;j<4;++j) p = fmaxf(p, acc[rt][mt][j]);
    p = fmaxf(p, __shfl_xor(p,16)); p = fmaxf(p, __shfl_xor(p,32));
    if (q4 == 0) rmS[w*64 + rt*16+m16] = p;
  }
  __syncthreads();   // rmS ready; proj/xbS reads done -> qS overlay safe
  unsigned short* qS = R0;
#pragma unroll
  for (int rt=0;rt<4;++rt){
    int rr = rt*16+m16;
    float rm = fmaxf(fmaxf(rmS[rr],rmS[64+rr]),fmaxf(rmS[128+rr],rmS[192+rr]));
    float e = diag4[rt] + rm;
#pragma unroll
    for (int mt=0;mt<4;++mt){
      float v0 = RATIO_*(__expf(acc[rt][mt][0]-e)+1e-4f);
      float v1 = RATIO_*(__expf(acc[rt][mt][1]-e)+1e-4f);
      float v2 = RATIO_*(__expf(acc[rt][mt][2]-e)+1e-4f);
      float v3 = RATIO_*(__expf(acc[rt][mt][3]-e)+1e-4f);
      *(uint2*)&qS[rr*264 + f0 + mt*16 + q4*4] = make_uint2(pk2f(v0,v1), pk2f(v2,v3));
    }
  }
  __syncthreads();
  bf16x8 aq[8];
#pragma unroll
  for (int kk=0;kk<8;++kk)
    aq[kk] = *(const bf16x8*)&qS[(r0+m16)*264 + kk*32 + q4*8];
  // q1 = rowsum(Q'[r0+m16])
  float q1v = 0.f;
#pragma unroll
  for (int kk=0;kk<8;++kk){
    union { bf16x8 v; unsigned u[4]; } av; av.v = aq[kk];
#pragma unroll
    for (int i=0;i<4;++i)
      q1v += b2f((unsigned short)av.u[i]) + b2f((unsigned short)(av.u[i]>>16));
  }
  q1v += __shfl_xor(q1v,16); q1v += __shfl_xor(q1v,32);
  __syncthreads();   // all qS reads done -> R0 free for oT later

  // main GEMMs: AL = Q'@Gr^T (kpL frags), accO = Q'@Sx (sxP frags)
  f32x4 accA[4], accO[5];
#pragma unroll
  for (int i=0;i<4;++i) accA[i] = (f32x4){0.f,0.f,0.f,0.f};
#pragma unroll
  for (int i=0;i<5;++i) accO[i] = (f32x4){0.f,0.f,0.f,0.f};
  const unsigned short* kpb = kpL + (size_t)ch*16384 + m16*32 + q4*8;
  const unsigned short* sxb = sxP + (size_t)ch*5*4096 + m16*32 + q4*8;
#pragma unroll
  for (int kk=0;kk<8;++kk){
    bf16x8 a = aq[kk];
#pragma unroll
    for (int st=0;st<4;++st)
      accA[st] = MFMA(a, *(const bf16x8*)(kpb + (size_t)st*4096 + kk*512), accA[st]);
#pragma unroll
    for (int ct=0;ct<5;++ct)
      accO[ct] = MFMA(a, *(const bf16x8*)(sxb + (size_t)ct*4096 + kk*512), accO[ct]);
  }
  // P = s_ch*AL + EPSC*q1 (masked); xbS dead -> P overlay
  const float sch = schS;
#pragma unroll
  for (int j=0;j<4;++j){
    int rr = r0 + q4*4 + j;
    float q1r = __shfl(q1v, q4*4 + j);
    float addc = EPSC_ * q1r;
#pragma unroll
    for (int st=0;st<4;++st){
      int cc = st*16 + m16;
      P[rr*72 + cc] = f2b((cc<=rr) ? (sch*accA[st][j] + addc) : 0.f);
    }
  }
#pragma unroll
  for (int k2=0;k2<2;++k2){
    bf16x8 aP = *(const bf16x8*)&P[(r0+m16)*72 + k2*32 + q4*8];
#pragma unroll
    for (int ct=0;ct<5;++ct){
      bf16x8 bfr = *(const bf16x8*)&C_[(ct*16+m16)*72 + k2*32 + q4*8];
      accO[ct] = MFMA(aP, bfr, accO[ct]);
    }
  }
  // epilogue via oT (overlay R0)
  float* oT = (float*)R0;
#pragma unroll
  for (int j=0;j<4;++j){
    float d64 = __shfl(accO[4][j], (lane & 48));
    float d65 = __shfl(accO[4][j], (lane & 48) | 1);
    float dinv = 1.f/(d64+d65);
    int rr = r0 + q4*4 + j;
#pragma unroll
    for (int ct=0;ct<4;++ct)
      oT[rr*68 + ct*16 + m16] = accO[ct][j]*dinv;
  }
  __syncthreads();
#pragma unroll
  for (int i=0;i<4;++i){ int flat=i*1024+t*4; int r=flat>>6, c2=flat&63;
    *(float4*)(out_g + (size_t)row0*64 + flat) = *(const float4*)&oT[r*68+c2]; }
}

extern "C" void kernel_launch(void* const* d_in, const int* in_sizes, int n_in,
                              void* d_out, int out_size, void* d_ws, size_t ws_size,
                              hipStream_t stream)
{
  (void)in_sizes; (void)n_in; (void)out_size; (void)ws_size;
  const float* q    = (const float*)d_in[0];
  const float* k    = (const float*)d_in[1];
  const float* v    = (const float*)d_in[2];
  const float* proj = (const float*)d_in[3];
  float* out = (float*)d_out;

  char* p8 = (char*)d_ws;
  unsigned short* kpL  = (unsigned short*)p8; p8 += (size_t)NCH_*16384*2;   // 16.78 MB
  unsigned short* kvxP = (unsigned short*)p8; p8 += (size_t)NCH_*5*4096*2;  // 20.97 MB
  unsigned short* sxP  = (unsigned short*)p8; p8 += (size_t)NCH_*5*4096*2;  // 20.97 MB
  float* blockmax = (float*)p8; p8 += NCH_*sizeof(float);
  float* vsumG    = (float*)p8;                                             // 512*80*4B

  kfeat_kernel<<<dim3(NCH_), dim3(256), 0, stream>>>(k, v, proj, kpL, kvxP,
                                                     blockmax, vsumG);
  scan_kernel <<<dim3(320),  dim3(256), 0, stream>>>(kvxP, sxP, blockmax, vsumG);
  out_kernel  <<<dim3(NCH_), dim3(256), 0, stream>>>(q, proj, kpL, sxP, v,
                                                     blockmax, out);
}

// Round 14
// 114.362 us; speedup vs baseline: 2.8735x; 1.0074x over previous
//
#include <hip/hip_runtime.h>
#include <hip/hip_bf16.h>
#include <cstddef>

typedef __attribute__((ext_vector_type(8))) short bf16x8;
typedef __attribute__((ext_vector_type(4))) float f32x4;

#define NCH_ 512
#define NRM_ 0.35355339059327373f  // 64^-0.25
#define RATIO_ 0.0625f             // 256^-0.5
#define EPSC_ 6.25e-6f             // RATIO_*1e-4 (k' eps, applied analytically)
#define MFMA(a,b,c) __builtin_amdgcn_mfma_f32_16x16x32_bf16((a),(b),(c),0,0,0)

__device__ __forceinline__ unsigned short f2b(float f) {
  unsigned u = __float_as_uint(f);
  u += 0x7FFFu + ((u >> 16) & 1u);
  return (unsigned short)(u >> 16);
}
__device__ __forceinline__ float b2f(unsigned short h) {
  return __uint_as_float(((unsigned)h) << 16);
}
__device__ __forceinline__ unsigned pk2f(float a, float b) {
  union { __hip_bfloat162 h; unsigned u; } cv;
  cv.h = __float22bfloat162_rn(make_float2(a, b));
  return cv.u;
}
__device__ __forceinline__ float sumsq4(float4 a){ return a.x*a.x+a.y*a.y+a.z*a.z+a.w*a.w; }

// K1: k chunk pass (no kpL output). Gr = RATIO*exp(xd-diag-cmax), chunk-local cmax.
// Writes: kvxP (B-frag-packed C2L = Vext^T@Gr), blockmax[ch]=cmax, vsumG[ch][c]=colsum(Vext).
__global__ __launch_bounds__(256, 2) void kfeat_kernel(
    const float* __restrict__ kg, const float* __restrict__ vg,
    const float* __restrict__ projg,
    unsigned short* __restrict__ kvxP,
    float* __restrict__ blockmax, float* __restrict__ vsumG)
{
  __shared__ unsigned short R0[256*72];   // proj bf16 -> overlay kpS [64][264]
  __shared__ unsigned short XB[128*72];   // xbS [64][72] -> overlay kpT [128][72]
  __shared__ unsigned short C_[80*72];    // vext [c][s]
  __shared__ float diagS[64];
  __shared__ float rmS[4];
  const int t=threadIdx.x, ch=blockIdx.x;
  const int row0 = ch*64;
  const int lane=t&63, m16=lane&15, q4=lane>>4, w=t>>6;
  const int f0 = w*64;
  unsigned short* kpS = R0;
  unsigned short* xbS = XB;
  unsigned short* kpT = XB;

#pragma unroll
  for (int i=0;i<8;++i){ int flat=i*2048+t*8; int f=flat>>6, d2=flat&63;
    float4 p0 = *(const float4*)(projg+flat);
    float4 p1 = *(const float4*)(projg+flat+4);
    *(uint4*)&R0[f*72+d2] = make_uint4(pk2f(p0.x,p0.y),pk2f(p0.z,p0.w),
                                       pk2f(p1.x,p1.y),pk2f(p1.z,p1.w)); }
  {  // k staging (bf16, scaled) + diag
    const float* xg = kg + (size_t)row0*64;
#pragma unroll
    for (int i=0;i<4;++i){
      int flat=i*1024+t*4; int r=flat>>6, d2=flat&63;
      float4 f = *(const float4*)(xg+flat);
      float ss = sumsq4(f);
      ss += __shfl_xor(ss,1); ss += __shfl_xor(ss,2);
      ss += __shfl_xor(ss,4); ss += __shfl_xor(ss,8);
      if ((t&15)==0) diagS[r] = 0.0625f*ss;
      *(uint2*)&xbS[r*72+d2] = make_uint2(pk2f(NRM_*f.x,NRM_*f.y), pk2f(NRM_*f.z,NRM_*f.w));
    }
  }
  {  // vext staging
    int c = t&63, sq_ = t>>6;
#pragma unroll
    for (int i=0;i<16;++i)
      C_[c*72 + sq_*16 + i] = f2b(vg[((size_t)row0 + sq_*16 + i)*64 + c]);
    int cc = 64 + (t>>4), s4 = (t&15)*4;
    unsigned short hv = (cc==64) ? (unsigned short)0x3F80 : (unsigned short)0;
    unsigned pv = (unsigned)hv | ((unsigned)hv<<16);
    *(uint2*)&C_[cc*72 + s4] = make_uint2(pv, pv);
  }
  __syncthreads();

  if (t < 80) {   // vsum = colsum(Vext)
    float s = 0.f;
#pragma unroll 16
    for (int i=0;i<64;++i) s += b2f(C_[t*72+i]);
    vsumG[(size_t)ch*80 + t] = s;
  }

  bf16x8 b[4][2]; float diag4[4];
#pragma unroll
  for (int rt=0;rt<4;++rt){
    b[rt][0] = *(const bf16x8*)&xbS[(rt*16+m16)*72 + q4*8];
    b[rt][1] = *(const bf16x8*)&xbS[(rt*16+m16)*72 + 32 + q4*8];
    diag4[rt] = diagS[rt*16+m16];
  }
  f32x4 acc[4][4];
#pragma unroll
  for (int rt=0;rt<4;++rt)
#pragma unroll
    for (int mt=0;mt<4;++mt) acc[rt][mt] = (f32x4){0.f,0.f,0.f,0.f};
#pragma unroll
  for (int kk=0;kk<2;++kk)
#pragma unroll
    for (int mt=0;mt<4;++mt){
      bf16x8 a = *(const bf16x8*)&R0[(f0+mt*16+m16)*72 + kk*32 + q4*8];
#pragma unroll
      for (int rt=0;rt<4;++rt)
        acc[rt][mt] = MFMA(a, b[rt][kk], acc[rt][mt]);
    }
  {  // chunk max
    float mx = acc[0][0][0];
#pragma unroll
    for (int rt=0;rt<4;++rt)
#pragma unroll
      for (int mt=0;mt<4;++mt)
#pragma unroll
        for (int j=0;j<4;++j) mx = fmaxf(mx, acc[rt][mt][j]);
#pragma unroll
    for (int off=1; off<64; off<<=1) mx = fmaxf(mx, __shfl_xor(mx, off));
    if (lane == 0) rmS[w] = mx;
  }
  __syncthreads();   // rmS ready; proj/xbS reads done -> overlays safe
  const float cmax = fmaxf(fmaxf(rmS[0],rmS[1]),fmaxf(rmS[2],rmS[3]));
  if (t == 0) blockmax[ch] = cmax;

  unsigned kpx[4][4][2];
#pragma unroll
  for (int rt=0;rt<4;++rt){
    float e = diag4[rt] + cmax;
    int rr = rt*16+m16;
#pragma unroll
    for (int mt=0;mt<4;++mt){
      float v0 = RATIO_*__expf(acc[rt][mt][0]-e);   // Gr (no eps — analytic)
      float v1 = RATIO_*__expf(acc[rt][mt][1]-e);
      float v2 = RATIO_*__expf(acc[rt][mt][2]-e);
      float v3 = RATIO_*__expf(acc[rt][mt][3]-e);
      kpx[rt][mt][0] = pk2f(v0,v1); kpx[rt][mt][1] = pk2f(v2,v3);
      *(uint2*)&kpS[rr*264 + f0 + mt*16 + q4*4] = make_uint2(kpx[rt][mt][0], kpx[rt][mt][1]);
    }
  }
  if ((w>>1) == 0) {   // kpT half 0 (features 0..127)
#pragma unroll
    for (int rt=0;rt<4;++rt)
#pragma unroll
      for (int mt=0;mt<4;++mt)
#pragma unroll
        for (int jp=0;jp<2;++jp){
          int frl = (w&1)*64 + mt*16 + q4*4 + jp*2;
          unsigned uv = kpx[rt][mt][jp];
          kpT[frl*72 + rt*16+m16]     = (unsigned short)uv;
          kpT[(frl+1)*72 + rt*16+m16] = (unsigned short)(uv>>16);
        }
  }
  __syncthreads();
  // chunk-sum GEMM halves -> kvxP (B-frag-packed), values = C2L (uncorrected)
#pragma unroll
  for (int h=0; h<2; ++h) {
    if (h == 1) {
      __syncthreads();
      if ((w>>1) == 1) {
#pragma unroll
        for (int rt=0;rt<4;++rt)
#pragma unroll
          for (int mt=0;mt<4;++mt)
#pragma unroll
            for (int jp=0;jp<2;++jp){
              int frl = (w&1)*64 + mt*16 + q4*4 + jp*2;
              unsigned uv = kpx[rt][mt][jp];
              kpT[frl*72 + rt*16+m16]     = (unsigned short)uv;
              kpT[(frl+1)*72 + rt*16+m16] = (unsigned short)(uv>>16);
            }
      }
      __syncthreads();
    }
    f32x4 c2a[5][2];
#pragma unroll
    for (int ct=0;ct<5;++ct)
#pragma unroll
      for (int p=0;p<2;++p) c2a[ct][p] = (f32x4){0.f,0.f,0.f,0.f};
#pragma unroll
    for (int kk=0;kk<2;++kk){
      bf16x8 av[5];
#pragma unroll
      for (int ct=0;ct<5;++ct)
        av[ct] = *(const bf16x8*)&C_[(ct*16+m16)*72 + kk*32 + q4*8];
#pragma unroll
      for (int p=0;p<2;++p){
        int mtl = w*2 + p;
        bf16x8 bv = *(const bf16x8*)&kpT[(mtl*16+m16)*72 + kk*32 + q4*8];
#pragma unroll
        for (int ct=0;ct<5;++ct)
          c2a[ct][p] = MFMA(av[ct], bv, c2a[ct][p]);
      }
    }
#pragma unroll
    for (int ct=0;ct<5;++ct)
#pragma unroll
      for (int p=0;p<2;++p){
        int mtg = h*8 + w*2 + p;
        int mrow = mtg*16 + m16;
        int fb = (mrow>>5)*512 + ((mrow>>3)&3)*8 + (mrow&7);
        unsigned short* dst = kvxP + (size_t)(ch*5+ct)*4096 + fb + (q4*4)*32;
#pragma unroll
        for (int j=0;j<4;++j)
          dst[j*32] = f2b(c2a[ct][p][j]);
      }
    if (h == 0) __syncthreads();
  }
}

// K2: exclusive prefix over 32 chunks with correction: contribution = s_chl*C2L + EPSC*vsum.
__global__ __launch_bounds__(256, 4) void scan_kernel(
    const unsigned short* __restrict__ kvxP, unsigned short* __restrict__ sxP,
    const float* __restrict__ blockmax, const float* __restrict__ vsumG)
{
  __shared__ float sS[32];
  __shared__ float vsS[32][16];
  const int t = threadIdx.x, bid = blockIdx.x;   // 0..319
  const int qtr = bid & 3, ct = (bid>>2)%5, bh = bid/20;
  if (t < 32) {
    float bm = blockmax[bh*32 + t];
    float km = bm;
#pragma unroll
    for (int off=16; off>=1; off>>=1) km = fmaxf(km, __shfl_xor(km, off));
    sS[t] = __expf(bm - km);
  }
  for (int i=t; i<512; i+=256){
    int chl = i>>4, c16 = i&15;
    vsS[chl][c16] = vsumG[(size_t)(bh*32+chl)*80 + ct*16 + c16];
  }
  __syncthreads();
  const int fbase = qtr*1024 + t*4;
  const int c16t = (t>>3)&15;
  const bool isEps = (ct==4) && (c16t == 1);
  float carry0=0.f, carry1=0.f, carry2=0.f, carry3=0.f;
  const size_t stride = (size_t)5*4096;
  size_t base = ((size_t)(bh*32)*5 + ct)*4096 + fbase;
#pragma unroll 4
  for (int chl=0; chl<32; ++chl){
    unsigned s0, s1;
    if (isEps) { unsigned ee = pk2f(1e-6f,1e-6f); s0 = ee; s1 = ee; }
    else { s0 = pk2f(carry0,carry1); s1 = pk2f(carry2,carry3); }
    *(uint2*)(sxP + base) = make_uint2(s0, s1);
    uint2 raw = *(const uint2*)(kvxP + base);
    float sch = sS[chl];
    float evs = EPSC_ * vsS[chl][c16t];
    carry0 += sch*b2f((unsigned short)(raw.x))     + evs;
    carry1 += sch*b2f((unsigned short)(raw.x>>16)) + evs;
    carry2 += sch*b2f((unsigned short)(raw.y))     + evs;
    carry3 += sch*b2f((unsigned short)(raw.y>>16)) + evs;
    base += stride;
  }
}

// K3: q-features + local Gr recompute + output, all in one block.
// R0 overlay sequence: proj -> qS -> kpS -> oT. Gr's cmax is recomputed locally
// (scale cancels in s_ch*AL, so any cmax is self-consistent).
__global__ __launch_bounds__(256, 2) void out_kernel(
    const float* __restrict__ qg, const float* __restrict__ kg,
    const float* __restrict__ projg, const unsigned short* __restrict__ sxP,
    const float* __restrict__ vg, const float* __restrict__ blockmax,
    float* __restrict__ out_g)
{
  __shared__ unsigned short R0[256*72];   // proj -> qS [64][264] -> kpS [64][264] -> oT f32[64][68]
  __shared__ unsigned short KX[64*72];    // k bf16 -> P [64][72]
  __shared__ unsigned short QX[64*72];    // q bf16
  __shared__ unsigned short C_[80*72];    // vext
  __shared__ float diagK[64];
  __shared__ float diagQ[64];
  __shared__ float rmS[4*64];
  __shared__ float cmS[4];
  __shared__ float schS;
  const int t=threadIdx.x, ch=blockIdx.x;
  const int row0 = ch*64;
  const int lane=t&63, m16=lane&15, q4=lane>>4, w=t>>6;
  const int f0 = w*64, r0 = w*16;
  unsigned short* P = KX;

#pragma unroll
  for (int i=0;i<8;++i){ int flat=i*2048+t*8; int f=flat>>6, d2=flat&63;
    float4 p0 = *(const float4*)(projg+flat);
    float4 p1 = *(const float4*)(projg+flat+4);
    *(uint4*)&R0[f*72+d2] = make_uint4(pk2f(p0.x,p0.y),pk2f(p0.z,p0.w),
                                       pk2f(p1.x,p1.y),pk2f(p1.z,p1.w)); }
  {  // k staging + diagK
    const float* xg = kg + (size_t)row0*64;
#pragma unroll
    for (int i=0;i<4;++i){
      int flat=i*1024+t*4; int r=flat>>6, d2=flat&63;
      float4 f = *(const float4*)(xg+flat);
      float ss = sumsq4(f);
      ss += __shfl_xor(ss,1); ss += __shfl_xor(ss,2);
      ss += __shfl_xor(ss,4); ss += __shfl_xor(ss,8);
      if ((t&15)==0) diagK[r] = 0.0625f*ss;
      *(uint2*)&KX[r*72+d2] = make_uint2(pk2f(NRM_*f.x,NRM_*f.y), pk2f(NRM_*f.z,NRM_*f.w));
    }
  }
  {  // q staging + diagQ
    const float* xg = qg + (size_t)row0*64;
#pragma unroll
    for (int i=0;i<4;++i){
      int flat=i*1024+t*4; int r=flat>>6, d2=flat&63;
      float4 f = *(const float4*)(xg+flat);
      float ss = sumsq4(f);
      ss += __shfl_xor(ss,1); ss += __shfl_xor(ss,2);
      ss += __shfl_xor(ss,4); ss += __shfl_xor(ss,8);
      if ((t&15)==0) diagQ[r] = 0.0625f*ss;
      *(uint2*)&QX[r*72+d2] = make_uint2(pk2f(NRM_*f.x,NRM_*f.y), pk2f(NRM_*f.z,NRM_*f.w));
    }
  }
  {  // vext staging
    int c = t&63, sq_ = t>>6;
#pragma unroll
    for (int i=0;i<16;++i)
      C_[c*72 + sq_*16 + i] = f2b(vg[((size_t)row0 + sq_*16 + i)*64 + c]);
    int cc = 64 + (t>>4), s4 = (t&15)*4;
    unsigned short hv = (cc==64) ? (unsigned short)0x3F80 : (unsigned short)0;
    unsigned pv = (unsigned)hv | ((unsigned)hv<<16);
    *(uint2*)&C_[cc*72 + s4] = make_uint2(pv, pv);
  }
  if (t < 32) {   // s_ch = exp(cmax_ch - kmax_bh), cmax from kfeat's blockmax
    float bm = blockmax[(ch>>5)*32 + t];
    float km = bm;
#pragma unroll
    for (int off=16; off>=1; off>>=1) km = fmaxf(km, __shfl_xor(km, off));
    if (t == (ch & 31)) schS = __expf(bm - km);
  }
  __syncthreads();

  // ---- both GEMMs (proj A-frags shared) ----
  bf16x8 bk[4][2], bq[4][2]; float dk4[4], dq4[4];
#pragma unroll
  for (int rt=0;rt<4;++rt){
    bk[rt][0] = *(const bf16x8*)&KX[(rt*16+m16)*72 + q4*8];
    bk[rt][1] = *(const bf16x8*)&KX[(rt*16+m16)*72 + 32 + q4*8];
    bq[rt][0] = *(const bf16x8*)&QX[(rt*16+m16)*72 + q4*8];
    bq[rt][1] = *(const bf16x8*)&QX[(rt*16+m16)*72 + 32 + q4*8];
    dk4[rt] = diagK[rt*16+m16];
    dq4[rt] = diagQ[rt*16+m16];
  }
  f32x4 kacc[4][4], qacc[4][4];
#pragma unroll
  for (int rt=0;rt<4;++rt)
#pragma unroll
    for (int mt=0;mt<4;++mt){ kacc[rt][mt] = (f32x4){0.f,0.f,0.f,0.f};
                              qacc[rt][mt] = (f32x4){0.f,0.f,0.f,0.f}; }
#pragma unroll
  for (int kk=0;kk<2;++kk)
#pragma unroll
    for (int mt=0;mt<4;++mt){
      bf16x8 a = *(const bf16x8*)&R0[(f0+mt*16+m16)*72 + kk*32 + q4*8];
#pragma unroll
      for (int rt=0;rt<4;++rt){
        kacc[rt][mt] = MFMA(a, bk[rt][kk], kacc[rt][mt]);
        qacc[rt][mt] = MFMA(a, bq[rt][kk], qacc[rt][mt]);
      }
    }
  // k cmax (local) + q per-row max
  {
    float mx = kacc[0][0][0];
#pragma unroll
    for (int rt=0;rt<4;++rt)
#pragma unroll
      for (int mt=0;mt<4;++mt)
#pragma unroll
        for (int j=0;j<4;++j) mx = fmaxf(mx, kacc[rt][mt][j]);
#pragma unroll
    for (int off=1; off<64; off<<=1) mx = fmaxf(mx, __shfl_xor(mx, off));
    if (lane == 0) cmS[w] = mx;
  }
#pragma unroll
  for (int rt=0;rt<4;++rt){
    float p = qacc[rt][0][0];
#pragma unroll
    for (int mt=0;mt<4;++mt)
#pragma unroll
      for (int j=0;j<4;++j) p = fmaxf(p, qacc[rt][mt][j]);
    p = fmaxf(p, __shfl_xor(p,16)); p = fmaxf(p, __shfl_xor(p,32));
    if (q4 == 0) rmS[w*64 + rt*16+m16] = p;
  }
  __syncthreads();   // reductions ready; all proj/KX/QX reads done
  const float cmax = fmaxf(fmaxf(cmS[0],cmS[1]),fmaxf(cmS[2],cmS[3]));

  // ---- q' -> qS (R0 overlay) -> aq regs + q1 ----
  unsigned short* qS = R0;
#pragma unroll
  for (int rt=0;rt<4;++rt){
    int rr = rt*16+m16;
    float rm = fmaxf(fmaxf(rmS[rr],rmS[64+rr]),fmaxf(rmS[128+rr],rmS[192+rr]));
    float e = dq4[rt] + rm;
#pragma unroll
    for (int mt=0;mt<4;++mt){
      float v0 = RATIO_*(__expf(qacc[rt][mt][0]-e)+1e-4f);
      float v1 = RATIO_*(__expf(qacc[rt][mt][1]-e)+1e-4f);
      float v2 = RATIO_*(__expf(qacc[rt][mt][2]-e)+1e-4f);
      float v3 = RATIO_*(__expf(qacc[rt][mt][3]-e)+1e-4f);
      *(uint2*)&qS[rr*264 + f0 + mt*16 + q4*4] = make_uint2(pk2f(v0,v1), pk2f(v2,v3));
    }
  }
  __syncthreads();
  bf16x8 aq[8];
#pragma unroll
  for (int kk=0;kk<8;++kk)
    aq[kk] = *(const bf16x8*)&qS[(r0+m16)*264 + kk*32 + q4*8];
  float q1v = 0.f;
#pragma unroll
  for (int kk=0;kk<8;++kk){
    union { bf16x8 v; unsigned u[4]; } av; av.v = aq[kk];
#pragma unroll
    for (int i=0;i<4;++i)
      q1v += b2f((unsigned short)av.u[i]) + b2f((unsigned short)(av.u[i]>>16));
  }
  q1v += __shfl_xor(q1v,16); q1v += __shfl_xor(q1v,32);
  __syncthreads();   // qS dead

  // ---- Gr -> kpS (R0 overlay) ----
  unsigned short* kpS = R0;
#pragma unroll
  for (int rt=0;rt<4;++rt){
    float e = dk4[rt] + cmax;
    int rr = rt*16+m16;
#pragma unroll
    for (int mt=0;mt<4;++mt){
      float v0 = RATIO_*__expf(kacc[rt][mt][0]-e);
      float v1 = RATIO_*__expf(kacc[rt][mt][1]-e);
      float v2 = RATIO_*__expf(kacc[rt][mt][2]-e);
      float v3 = RATIO_*__expf(kacc[rt][mt][3]-e);
      *(uint2*)&kpS[rr*264 + f0 + mt*16 + q4*4] = make_uint2(pk2f(v0,v1), pk2f(v2,v3));
    }
  }
  __syncthreads();

  // ---- main GEMMs: AL = Q'@Gr^T (kpS LDS frags), accO = Q'@Sx (sxP global frags) ----
  f32x4 accA[4], accO[5];
#pragma unroll
  for (int i=0;i<4;++i) accA[i] = (f32x4){0.f,0.f,0.f,0.f};
#pragma unroll
  for (int i=0;i<5;++i) accO[i] = (f32x4){0.f,0.f,0.f,0.f};
  const unsigned short* sxb = sxP + (size_t)ch*5*4096 + m16*32 + q4*8;
#pragma unroll
  for (int kk=0;kk<8;++kk){
    bf16x8 a = aq[kk];
#pragma unroll
    for (int st=0;st<4;++st){
      bf16x8 bfr = *(const bf16x8*)&kpS[(st*16+m16)*264 + kk*32 + q4*8];
      accA[st] = MFMA(a, bfr, accA[st]);
    }
#pragma unroll
    for (int ct=0;ct<5;++ct)
      accO[ct] = MFMA(a, *(const bf16x8*)(sxb + (size_t)ct*4096 + kk*512), accO[ct]);
  }
  __syncthreads();   // kpS reads done; KX dead -> P overlay safe
  // ---- P = s_ch*AL + EPSC*q1 (masked) ----
  const float sch = schS;
#pragma unroll
  for (int j=0;j<4;++j){
    int rr = r0 + q4*4 + j;
    float q1r = __shfl(q1v, q4*4 + j);
    float addc = EPSC_ * q1r;
#pragma unroll
    for (int st=0;st<4;++st){
      int cc = st*16 + m16;
      P[rr*72 + cc] = f2b((cc<=rr) ? (sch*accA[st][j] + addc) : 0.f);
    }
  }
#pragma unroll
  for (int k2=0;k2<2;++k2){
    bf16x8 aP = *(const bf16x8*)&P[(r0+m16)*72 + k2*32 + q4*8];
#pragma unroll
    for (int ct=0;ct<5;++ct){
      bf16x8 bfr = *(const bf16x8*)&C_[(ct*16+m16)*72 + k2*32 + q4*8];
      accO[ct] = MFMA(aP, bfr, accO[ct]);
    }
  }
  __syncthreads();   // P reads done; R0 free -> oT overlay
  float* oT = (float*)R0;
#pragma unroll
  for (int j=0;j<4;++j){
    float d64 = __shfl(accO[4][j], (lane & 48));
    float d65 = __shfl(accO[4][j], (lane & 48) | 1);
    float dinv = 1.f/(d64+d65);
    int rr = r0 + q4*4 + j;
#pragma unroll
    for (int ct=0;ct<4;++ct)
      oT[rr*68 + ct*16 + m16] = accO[ct][j]*dinv;
  }
  __syncthreads();
#pragma unroll
  for (int i=0;i<4;++i){ int flat=i*1024+t*4; int r=flat>>6, c2=flat&63;
    *(float4*)(out_g + (size_t)row0*64 + flat) = *(const float4*)&oT[r*68+c2]; }
}

extern "C" void kernel_launch(void* const* d_in, const int* in_sizes, int n_in,
                              void* d_out, int out_size, void* d_ws, size_t ws_size,
                              hipStream_t stream)
{
  (void)in_sizes; (void)n_in; (void)out_size; (void)ws_size;
  const float* q    = (const float*)d_in[0];
  const float* k    = (const float*)d_in[1];
  const float* v    = (const float*)d_in[2];
  const float* proj = (const float*)d_in[3];
  float* out = (float*)d_out;

  char* p8 = (char*)d_ws;
  unsigned short* kvxP = (unsigned short*)p8; p8 += (size_t)NCH_*5*4096*2;  // 20.97 MB
  unsigned short* sxP  = (unsigned short*)p8; p8 += (size_t)NCH_*5*4096*2;  // 20.97 MB
  float* blockmax = (float*)p8; p8 += NCH_*sizeof(float);
  float* vsumG    = (float*)p8;                                             // 512*80*4B

  kfeat_kernel<<<dim3(NCH_), dim3(256), 0, stream>>>(k, v, proj, kvxP,
                                                     blockmax, vsumG);
  scan_kernel <<<dim3(320),  dim3(256), 0, stream>>>(kvxP, sxP, blockmax, vsumG);
  out_kernel  <<<dim3(NCH_), dim3(256), 0, stream>>>(q, k, proj, sxP, v,
                                                     blockmax, out);
}